// Round 8
// baseline (168.706 us; speedup 1.0000x reference)
//
#include <hip/hip_runtime.h>

// GCN: 3 layers, h = relu(h + GCNConv(h)), fixed graph, f32 in/out.
// Single bf16 g plane (8MB, L3-resident). Gather: wave/node, paired-row
// dwordx2 loads (2 rows / load instr, 16 rows in flight), branch-free tail
// via zero pad row. h carried bf16 (hb) between layers; layer-0 reads x f32.

typedef __attribute__((ext_vector_type(8))) short short8;   // 8 bf16 = 4 VGPR
typedef __attribute__((ext_vector_type(4))) float f32x4;

__device__ inline ushort f2bf(float f) {           // RNE f32 -> bf16
    union { float f; unsigned u; } v; v.f = f;
    unsigned u = v.u;
    return (ushort)((u + 0x7fffu + ((u >> 16) & 1u)) >> 16);
}
__device__ inline float2 bf2f(unsigned u) {        // two packed bf16 -> float2
    union { unsigned i; float f; } a, b;
    a.i = u << 16;
    b.i = u & 0xffff0000u;
    return make_float2(a.f, b.f);
}
__device__ inline f32x4 bf4(uint2 v) {             // 4 packed bf16 -> f32x4
    float2 a = bf2f(v.x), b = bf2f(v.y);
    f32x4 r = { a.x, a.y, b.x, b.y };
    return r;
}
__device__ inline short8 pack8(f32x4 a, f32x4 b) { // 8 f32 -> short8 bf16
    short8 r = { (short)f2bf(a.x), (short)f2bf(a.y), (short)f2bf(a.z), (short)f2bf(a.w),
                 (short)f2bf(b.x), (short)f2bf(b.y), (short)f2bf(b.z), (short)f2bf(b.w) };
    return r;
}

// ---------------- degree ----------------
__global__ void k_deg(const int* __restrict__ col, int* __restrict__ deg, int E) {
    int i = blockIdx.x * blockDim.x + threadIdx.x;
    if (i < E) atomicAdd(&deg[col[i]], 1);
}

// ---------------- hierarchical exclusive scan ----------------
__global__ __launch_bounds__(256) void k_scan1(const int* __restrict__ deg,
                                               int* __restrict__ offs,
                                               int* __restrict__ bsum, int n) {
    __shared__ int sm[256];
    int t = threadIdx.x, i = blockIdx.x * 256 + t;
    int v = (i < n) ? deg[i] : 0;
    sm[t] = v;
    __syncthreads();
    for (int off = 1; off < 256; off <<= 1) {
        int u = (t >= off) ? sm[t - off] : 0;
        __syncthreads();
        sm[t] += u;
        __syncthreads();
    }
    if (i < n) offs[i] = sm[t] - v;
    if (t == 255) bsum[blockIdx.x] = sm[255];
}

__global__ __launch_bounds__(128) void k_scan2(int* __restrict__ bsum, int nb) {
    __shared__ int sm[128];
    int t = threadIdx.x;
    int v = (t < nb) ? bsum[t] : 0;
    sm[t] = v;
    __syncthreads();
    for (int off = 1; off < 128; off <<= 1) {
        int u = (t >= off) ? sm[t - off] : 0;
        __syncthreads();
        sm[t] += u;
        __syncthreads();
    }
    if (t < nb) bsum[t] = sm[t] - v;
}

// offs final; cnt = CSR cursor; dis = rsqrt(deg+1); zero g pad row
__global__ __launch_bounds__(256) void k_scan3(int* __restrict__ offs,
                                               const int* __restrict__ bsum,
                                               const int* __restrict__ deg,
                                               int* __restrict__ cnt,
                                               float* __restrict__ dis,
                                               unsigned* __restrict__ g,
                                               int n, int E) {
    int i = blockIdx.x * 256 + threadIdx.x;
    if (i < n) {
        int o = offs[i] + bsum[blockIdx.x];
        offs[i] = o;
        cnt[i] = o;
        dis[i] = rsqrtf((float)(deg[i] + 1));
    }
    if (i == 0) offs[n] = E;
    if (i < 64) g[(size_t)n * 64 + i] = 0;   // pad row (branch-free gather tail)
}

// ---------------- CSR build (ushort indices; order nondeterministic) ----------
__global__ void k_csr(const int* __restrict__ row, const int* __restrict__ col,
                      int* __restrict__ cnt, ushort* __restrict__ csru, int E) {
    int i = blockIdx.x * blockDim.x + threadIdx.x;
    if (i < E) {
        int c = col[i];
        int p = atomicAdd(&cnt[c], 1);
        csru[p] = (ushort)row[i];
    }
}

// ---------------- MFMA GEMM core (A-frags passed in) ----------------
// Shared W handling: in-kernel transpose to XOR-swizzled LDS.
#define GEMM_BODY(A0, A1, A2, A3)                                               \
    f32x4 acc[8] = {};                                                          \
    _Pragma("unroll")                                                           \
    for (int nf = 0; nf < 8; ++nf) {                                            \
        const unsigned* wr = &Wl[nf * 16 + c][0];                               \
        int sx = (c & 7) << 2;                                                  \
        int b = q * 4;                                                          \
        short8 b0 = *(const short8*)(wr + ((b +  0) ^ sx));                     \
        short8 b1 = *(const short8*)(wr + ((b + 16) ^ sx));                     \
        short8 b2 = *(const short8*)(wr + ((b + 32) ^ sx));                     \
        short8 b3 = *(const short8*)(wr + ((b + 48) ^ sx));                     \
        acc[nf] = __builtin_amdgcn_mfma_f32_16x16x32_bf16(A0, b0, acc[nf], 0, 0, 0); \
        acc[nf] = __builtin_amdgcn_mfma_f32_16x16x32_bf16(A1, b1, acc[nf], 0, 0, 0); \
        acc[nf] = __builtin_amdgcn_mfma_f32_16x16x32_bf16(A2, b2, acc[nf], 0, 0, 0); \
        acc[nf] = __builtin_amdgcn_mfma_f32_16x16x32_bf16(A3, b3, acc[nf], 0, 0, 0); \
    }                                                                           \
    float d0 = dis[rb + q * 4 + 0], d1 = dis[rb + q * 4 + 1];                   \
    float d2 = dis[rb + q * 4 + 2], d3 = dis[rb + q * 4 + 3];                   \
    _Pragma("unroll")                                                           \
    for (int nf = 0; nf < 8; ++nf) {                                            \
        int gc = nf * 16 + c;                                                   \
        g[(size_t)(rb + q * 4 + 0) * 128 + gc] = f2bf(acc[nf][0] * d0);         \
        g[(size_t)(rb + q * 4 + 1) * 128 + gc] = f2bf(acc[nf][1] * d1);         \
        g[(size_t)(rb + q * 4 + 2) * 128 + gc] = f2bf(acc[nf][2] * d2);         \
        g[(size_t)(rb + q * 4 + 3) * 128 + gc] = f2bf(acc[nf][3] * d3);         \
    }

#define W_STAGE                                                                  \
    __shared__ unsigned Wl[128][64];                                             \
    int tid = threadIdx.x;                                                       \
    {                                                                            \
        int nn = tid & 127, hf = tid >> 7;                                       \
        for (int qq = 0; qq < 32; ++qq) {                                        \
            int k2 = hf * 32 + qq;                                               \
            float lo = W[(size_t)(2 * k2) * 128 + nn];                           \
            float hi = W[(size_t)(2 * k2 + 1) * 128 + nn];                       \
            Wl[nn][k2 ^ ((nn & 7) << 2)] = ((unsigned)f2bf(hi) << 16) | f2bf(lo);\
        }                                                                        \
    }                                                                            \
    __syncthreads();                                                             \
    int w = tid >> 6, l = tid & 63;                                              \
    int rb = blockIdx.x * 64 + w * 16;                                           \
    int c = l & 15, q = l >> 4;

// Layers 1..: A from bf16 hb
__global__ __launch_bounds__(256) void k_gemm(const unsigned* __restrict__ hb,
                                              const float* __restrict__ W,
                                              const float* __restrict__ dis,
                                              ushort* __restrict__ g, int n) {
    W_STAGE
    const short8* arow = (const short8*)(hb + (size_t)(rb + c) * 64);
    short8 a0 = arow[q], a1 = arow[4 + q], a2 = arow[8 + q], a3 = arow[12 + q];
    GEMM_BODY(a0, a1, a2, a3)
}

// Layer 0: A from f32 x, converted inline
__global__ __launch_bounds__(256) void k_gemm0(const float* __restrict__ x,
                                               const float* __restrict__ W,
                                               const float* __restrict__ dis,
                                               ushort* __restrict__ g, int n) {
    W_STAGE
    const f32x4* xr = (const f32x4*)(x + (size_t)(rb + c) * 128);
    short8 a0 = pack8(xr[q * 2 +  0], xr[q * 2 +  1]);
    short8 a1 = pack8(xr[q * 2 +  8], xr[q * 2 +  9]);
    short8 a2 = pack8(xr[q * 2 + 16], xr[q * 2 + 17]);
    short8 a3 = pack8(xr[q * 2 + 24], xr[q * 2 + 25]);
    GEMM_BODY(a0, a1, a2, a3)
}

// ---------------- gather: out = relu(resid + dis[c]*(g[c] + sum g[nbr]) + b) ----
// Wave per node. Paired-row loads: lanes 0-31 take row t+2u, lanes 32-63 take
// row t+2u+1, dwordx2 (4 bf16) per lane -> one instr = 2 rows (512B).
// 8 load instrs = 16 rows in flight. Tail padded to 16 rows via zero row n.
__global__ __launch_bounds__(256) void k_gather(const unsigned* __restrict__ g,
                                                unsigned* __restrict__ hb,
                                                const float* __restrict__ dis,
                                                const float* __restrict__ bias,
                                                const int* __restrict__ offs,
                                                const ushort* __restrict__ csru,
                                                const float* __restrict__ xres,
                                                float* __restrict__ outp,
                                                int n, int use_x, int last) {
    int wid = threadIdx.x >> 6, lane = threadIdx.x & 63;
    int node = blockIdx.x * 4 + wid;
    if (node >= n) return;
    int half = lane >> 5, fl = lane & 31;
    int fo8 = fl * 8;
    const char* gb = (const char*)g;

    // self-loop: lanes 0-31 row node, lanes 32-63 zero pad row
    uint2 sv = *(const uint2*)(gb + ((size_t)(half ? n : node) << 8) + fo8);
    f32x4 acc = bf4(sv);

    int s = offs[node];
    int deg = offs[node + 1] - s;
    for (int j0 = 0; j0 < deg; j0 += 64) {
        int rem = deg - j0;
        int m = rem < 64 ? rem : 64;
        int idx = (lane < m) ? (int)__builtin_nontemporal_load(&csru[s + j0 + lane]) : n;
        int mc = (m + 15) & ~15;
        for (int t = 0; t < mc; t += 16) {
            uint2 v[8];
#pragma unroll
            for (int u = 0; u < 8; ++u) {
                int r = __shfl(idx, t + 2 * u + half, 64);
                v[u] = *(const uint2*)(gb + ((size_t)r << 8) + fo8);
            }
            f32x4 s0 = (bf4(v[0]) + bf4(v[1])) + (bf4(v[2]) + bf4(v[3]));
            f32x4 s1 = (bf4(v[4]) + bf4(v[5])) + (bf4(v[6]) + bf4(v[7]));
            acc += s0 + s1;
        }
    }
    // fold row-halves: lanes 0-31 accumulate lanes 32-63
    acc.x += __shfl_xor(acc.x, 32, 64);
    acc.y += __shfl_xor(acc.y, 32, 64);
    acc.z += __shfl_xor(acc.z, 32, 64);
    acc.w += __shfl_xor(acc.w, 32, 64);

    if (half == 0) {
        float d = dis[node];
        f32x4 bv = ((const f32x4*)bias)[fl];
        f32x4 hv;
        if (use_x) {
            hv = ((const f32x4*)xres)[(size_t)node * 32 + fl];
        } else {
            uint2 h2 = *(const uint2*)((const char*)hb + ((size_t)node << 8) + fo8);
            hv = bf4(h2);
        }
        f32x4 o = acc * d + hv + bv;
        o.x = fmaxf(o.x, 0.f); o.y = fmaxf(o.y, 0.f);
        o.z = fmaxf(o.z, 0.f); o.w = fmaxf(o.w, 0.f);
        if (last) {
            __builtin_nontemporal_store(o, (f32x4*)&outp[(size_t)node * 128 + fl * 4]);
        } else {
            uint2 pk;
            pk.x = ((unsigned)f2bf(o.y) << 16) | f2bf(o.x);
            pk.y = ((unsigned)f2bf(o.w) << 16) | f2bf(o.z);
            *(uint2*)((char*)hb + ((size_t)node << 8) + fo8) = pk;
        }
    }
}

static inline size_t al256(size_t x) { return (x + 255) & ~(size_t)255; }

extern "C" void kernel_launch(void* const* d_in, const int* in_sizes, int n_in,
                              void* d_out, int out_size, void* d_ws, size_t ws_size,
                              hipStream_t stream) {
    const float* x  = (const float*)d_in[0];
    const int*   ei = (const int*)d_in[1];
    const float* Ws = (const float*)d_in[2];
    const float* bs = (const float*)d_in[3];
    int n  = in_sizes[0] / 128;          // 32768 nodes
    int E  = in_sizes[1] / 2;            // 524288 edges
    int NL = in_sizes[2] / (128 * 128);  // 3 layers
    const int* rowp = ei;
    const int* colp = ei + E;

    char* ws = (char*)d_ws;
    size_t plane = al256((size_t)(n + 1) * 256);     // (n+1) rows x 256B
    unsigned* g  = (unsigned*)ws;
    unsigned* hb = (unsigned*)(ws + plane);
    char* p = ws + 2 * plane;
    float* dis  = (float*)p;               p += al256((size_t)n * 4);
    int*   deg  = (int*)p;                 p += al256((size_t)n * 4);
    int*   offs = (int*)p;                 p += al256((size_t)(n + 1) * 4);
    int*   cnt  = (int*)p;                 p += al256((size_t)n * 4);
    int*   bsum = (int*)p;                 p += 512;
    ushort* csru = (ushort*)p;

    int nb = (n + 255) / 256;            // 128 scan blocks

    (void)hipMemsetAsync(deg, 0, (size_t)n * 4, stream);
    k_deg<<<(E + 255) / 256, 256, 0, stream>>>(colp, deg, E);
    k_scan1<<<nb, 256, 0, stream>>>(deg, offs, bsum, n);
    k_scan2<<<1, 128, 0, stream>>>(bsum, nb);
    k_scan3<<<nb, 256, 0, stream>>>(offs, bsum, deg, cnt, dis, g, n, E);
    k_csr<<<(E + 255) / 256, 256, 0, stream>>>(rowp, colp, cnt, csru, E);

    for (int l = 0; l < NL; ++l) {
        int last = (l + 1 == NL);
        const float* Wl = Ws + (size_t)l * 128 * 128;
        if (l == 0)
            k_gemm0<<<n / 64, 256, 0, stream>>>(x, Wl, dis, (ushort*)g, n);
        else
            k_gemm<<<n / 64, 256, 0, stream>>>(hb, Wl, dis, (ushort*)g, n);
        k_gather<<<(n + 3) / 4, 256, 0, stream>>>(g, hb, dis,
                                                  bs + (size_t)l * 128,
                                                  offs, csru, x,
                                                  (float*)d_out, n,
                                                  l == 0, last);
    }
}

// Round 9
// 151.200 us; speedup vs baseline: 1.1158x; 1.1158x over previous
//
#include <hip/hip_runtime.h>

// GCN: 3 layers, h = relu(h + GCNConv(h)), fixed graph, f32 in/out.
// Message plane g in OCP fp8 e4m3 (128B rows) -> random-gather traffic halved
// again (134MB -> 67MB per layer). h carried bf16 (hb); layer-0 reads x f32.

typedef __attribute__((ext_vector_type(8))) short short8;   // 8 bf16 = 4 VGPR
typedef __attribute__((ext_vector_type(4))) float f32x4;
typedef __attribute__((ext_vector_type(2))) float f32x2;

__device__ inline ushort f2bf(float f) {           // RNE f32 -> bf16
    union { float f; unsigned u; } v; v.f = f;
    unsigned u = v.u;
    return (ushort)((u + 0x7fffu + ((u >> 16) & 1u)) >> 16);
}
__device__ inline float2 bf2f(unsigned u) {        // two packed bf16 -> float2
    union { unsigned i; float f; } a, b;
    a.i = u << 16;
    b.i = u & 0xffff0000u;
    return make_float2(a.f, b.f);
}
__device__ inline f32x4 bf4(uint2 v) {             // 4 packed bf16 -> f32x4
    float2 a = bf2f(v.x), b = bf2f(v.y);
    f32x4 r = { a.x, a.y, b.x, b.y };
    return r;
}
__device__ inline short8 pack8(f32x4 a, f32x4 b) { // 8 f32 -> short8 bf16
    short8 r = { (short)f2bf(a.x), (short)f2bf(a.y), (short)f2bf(a.z), (short)f2bf(a.w),
                 (short)f2bf(b.x), (short)f2bf(b.y), (short)f2bf(b.z), (short)f2bf(b.w) };
    return r;
}
__device__ inline unsigned char f2fp8(float f) {   // f32 -> e4m3 (HW RNE)
    return (unsigned char)(__builtin_amdgcn_cvt_pk_fp8_f32(f, f, 0, false) & 0xff);
}
__device__ inline f32x4 fp8x4(unsigned v) {        // 4 packed e4m3 -> f32x4
    f32x2 lo = __builtin_amdgcn_cvt_pk_f32_fp8((int)v, false);
    f32x2 hi = __builtin_amdgcn_cvt_pk_f32_fp8((int)v, true);
    f32x4 r = { lo.x, lo.y, hi.x, hi.y };
    return r;
}

// ---------------- degree ----------------
__global__ void k_deg(const int* __restrict__ col, int* __restrict__ deg, int E) {
    int i = blockIdx.x * blockDim.x + threadIdx.x;
    if (i < E) atomicAdd(&deg[col[i]], 1);
}

// ---------------- hierarchical exclusive scan ----------------
__global__ __launch_bounds__(256) void k_scan1(const int* __restrict__ deg,
                                               int* __restrict__ offs,
                                               int* __restrict__ bsum, int n) {
    __shared__ int sm[256];
    int t = threadIdx.x, i = blockIdx.x * 256 + t;
    int v = (i < n) ? deg[i] : 0;
    sm[t] = v;
    __syncthreads();
    for (int off = 1; off < 256; off <<= 1) {
        int u = (t >= off) ? sm[t - off] : 0;
        __syncthreads();
        sm[t] += u;
        __syncthreads();
    }
    if (i < n) offs[i] = sm[t] - v;
    if (t == 255) bsum[blockIdx.x] = sm[255];
}

__global__ __launch_bounds__(128) void k_scan2(int* __restrict__ bsum, int nb) {
    __shared__ int sm[128];
    int t = threadIdx.x;
    int v = (t < nb) ? bsum[t] : 0;
    sm[t] = v;
    __syncthreads();
    for (int off = 1; off < 128; off <<= 1) {
        int u = (t >= off) ? sm[t - off] : 0;
        __syncthreads();
        sm[t] += u;
        __syncthreads();
    }
    if (t < nb) bsum[t] = sm[t] - v;
}

// offs final; cnt = CSR cursor; dis = rsqrt(deg+1); zero g pad row
__global__ __launch_bounds__(256) void k_scan3(int* __restrict__ offs,
                                               const int* __restrict__ bsum,
                                               const int* __restrict__ deg,
                                               int* __restrict__ cnt,
                                               float* __restrict__ dis,
                                               unsigned* __restrict__ g32,
                                               int n, int E) {
    int i = blockIdx.x * 256 + threadIdx.x;
    if (i < n) {
        int o = offs[i] + bsum[blockIdx.x];
        offs[i] = o;
        cnt[i] = o;
        dis[i] = rsqrtf((float)(deg[i] + 1));
    }
    if (i == 0) offs[n] = E;
    if (i < 32) g32[(size_t)n * 32 + i] = 0;  // 128B pad row (branch-free tail)
}

// ---------------- CSR build (ushort indices; order nondeterministic) ----------
__global__ void k_csr(const int* __restrict__ row, const int* __restrict__ col,
                      int* __restrict__ cnt, ushort* __restrict__ csru, int E) {
    int i = blockIdx.x * blockDim.x + threadIdx.x;
    if (i < E) {
        int c = col[i];
        int p = atomicAdd(&cnt[c], 1);
        csru[p] = (ushort)row[i];
    }
}

// ---------------- MFMA GEMM core (A-frags passed in) ----------------
#define GEMM_BODY(A0, A1, A2, A3)                                               \
    f32x4 acc[8] = {};                                                          \
    _Pragma("unroll")                                                           \
    for (int nf = 0; nf < 8; ++nf) {                                            \
        const unsigned* wr = &Wl[nf * 16 + c][0];                               \
        int sx = (c & 7) << 2;                                                  \
        int b = q * 4;                                                          \
        short8 b0 = *(const short8*)(wr + ((b +  0) ^ sx));                     \
        short8 b1 = *(const short8*)(wr + ((b + 16) ^ sx));                     \
        short8 b2 = *(const short8*)(wr + ((b + 32) ^ sx));                     \
        short8 b3 = *(const short8*)(wr + ((b + 48) ^ sx));                     \
        acc[nf] = __builtin_amdgcn_mfma_f32_16x16x32_bf16(A0, b0, acc[nf], 0, 0, 0); \
        acc[nf] = __builtin_amdgcn_mfma_f32_16x16x32_bf16(A1, b1, acc[nf], 0, 0, 0); \
        acc[nf] = __builtin_amdgcn_mfma_f32_16x16x32_bf16(A2, b2, acc[nf], 0, 0, 0); \
        acc[nf] = __builtin_amdgcn_mfma_f32_16x16x32_bf16(A3, b3, acc[nf], 0, 0, 0); \
    }                                                                           \
    float d0 = dis[rb + q * 4 + 0], d1 = dis[rb + q * 4 + 1];                   \
    float d2 = dis[rb + q * 4 + 2], d3 = dis[rb + q * 4 + 3];                   \
    _Pragma("unroll")                                                           \
    for (int nf = 0; nf < 8; ++nf) {                                            \
        int gc = nf * 16 + c;                                                   \
        g[(size_t)(rb + q * 4 + 0) * 128 + gc] = f2fp8(acc[nf][0] * d0);        \
        g[(size_t)(rb + q * 4 + 1) * 128 + gc] = f2fp8(acc[nf][1] * d1);        \
        g[(size_t)(rb + q * 4 + 2) * 128 + gc] = f2fp8(acc[nf][2] * d2);        \
        g[(size_t)(rb + q * 4 + 3) * 128 + gc] = f2fp8(acc[nf][3] * d3);        \
    }

#define W_STAGE                                                                  \
    __shared__ unsigned Wl[128][64];                                             \
    int tid = threadIdx.x;                                                       \
    {                                                                            \
        int nn = tid & 127, hf = tid >> 7;                                       \
        for (int qq = 0; qq < 32; ++qq) {                                        \
            int k2 = hf * 32 + qq;                                               \
            float lo = W[(size_t)(2 * k2) * 128 + nn];                           \
            float hi = W[(size_t)(2 * k2 + 1) * 128 + nn];                       \
            Wl[nn][k2 ^ ((nn & 7) << 2)] = ((unsigned)f2bf(hi) << 16) | f2bf(lo);\
        }                                                                        \
    }                                                                            \
    __syncthreads();                                                             \
    int w = tid >> 6, l = tid & 63;                                              \
    int rb = blockIdx.x * 64 + w * 16;                                           \
    int c = l & 15, q = l >> 4;

// Layers 1..: A from bf16 hb
__global__ __launch_bounds__(256) void k_gemm(const unsigned* __restrict__ hb,
                                              const float* __restrict__ W,
                                              const float* __restrict__ dis,
                                              unsigned char* __restrict__ g, int n) {
    W_STAGE
    const short8* arow = (const short8*)(hb + (size_t)(rb + c) * 64);
    short8 a0 = arow[q], a1 = arow[4 + q], a2 = arow[8 + q], a3 = arow[12 + q];
    GEMM_BODY(a0, a1, a2, a3)
}

// Layer 0: A from f32 x, converted inline
__global__ __launch_bounds__(256) void k_gemm0(const float* __restrict__ x,
                                               const float* __restrict__ W,
                                               const float* __restrict__ dis,
                                               unsigned char* __restrict__ g, int n) {
    W_STAGE
    const f32x4* xr = (const f32x4*)(x + (size_t)(rb + c) * 128);
    short8 a0 = pack8(xr[q * 2 +  0], xr[q * 2 +  1]);
    short8 a1 = pack8(xr[q * 2 +  8], xr[q * 2 +  9]);
    short8 a2 = pack8(xr[q * 2 + 16], xr[q * 2 + 17]);
    short8 a3 = pack8(xr[q * 2 + 24], xr[q * 2 + 25]);
    GEMM_BODY(a0, a1, a2, a3)
}

// ---------------- gather: out = relu(resid + dis[c]*(g[c] + sum g[nbr]) + b) ----
// Wave per node. fp8 rows = 128B: paired-row loads (lanes 0-31 row t+2u,
// lanes 32-63 row t+2u+1, 1 dword = 4 fp8 per lane). 8 loads = 16 rows in
// flight. Tail padded to 16 rows via zero row n.
__global__ __launch_bounds__(256) void k_gather(const unsigned* __restrict__ g,
                                                unsigned* __restrict__ hb,
                                                const float* __restrict__ dis,
                                                const float* __restrict__ bias,
                                                const int* __restrict__ offs,
                                                const ushort* __restrict__ csru,
                                                const float* __restrict__ xres,
                                                float* __restrict__ outp,
                                                int n, int use_x, int last) {
    int wid = threadIdx.x >> 6, lane = threadIdx.x & 63;
    int node = blockIdx.x * 4 + wid;
    if (node >= n) return;
    int half = lane >> 5, fl = lane & 31;
    int fo4 = fl * 4;
    const char* gb = (const char*)g;

    // self-loop: lanes 0-31 row node, lanes 32-63 zero pad row
    unsigned sv = *(const unsigned*)(gb + ((size_t)(half ? n : node) << 7) + fo4);
    f32x4 acc = fp8x4(sv);

    int s = offs[node];
    int deg = offs[node + 1] - s;
    for (int j0 = 0; j0 < deg; j0 += 64) {
        int rem = deg - j0;
        int m = rem < 64 ? rem : 64;
        int idx = (lane < m) ? (int)__builtin_nontemporal_load(&csru[s + j0 + lane]) : n;
        int mc = (m + 15) & ~15;
        for (int t = 0; t < mc; t += 16) {
            unsigned v[8];
#pragma unroll
            for (int u = 0; u < 8; ++u) {
                int r = __shfl(idx, t + 2 * u + half, 64);
                v[u] = *(const unsigned*)(gb + ((size_t)r << 7) + fo4);
            }
            f32x4 s0 = (fp8x4(v[0]) + fp8x4(v[1])) + (fp8x4(v[2]) + fp8x4(v[3]));
            f32x4 s1 = (fp8x4(v[4]) + fp8x4(v[5])) + (fp8x4(v[6]) + fp8x4(v[7]));
            acc += s0 + s1;
        }
    }
    // fold row-halves: lanes 0-31 accumulate lanes 32-63
    acc.x += __shfl_xor(acc.x, 32, 64);
    acc.y += __shfl_xor(acc.y, 32, 64);
    acc.z += __shfl_xor(acc.z, 32, 64);
    acc.w += __shfl_xor(acc.w, 32, 64);

    if (half == 0) {
        float d = dis[node];
        f32x4 bv = ((const f32x4*)bias)[fl];
        f32x4 hv;
        if (use_x) {
            hv = ((const f32x4*)xres)[(size_t)node * 32 + fl];
        } else {
            uint2 h2 = *(const uint2*)((const char*)hb + ((size_t)node << 8) + fl * 8);
            hv = bf4(h2);
        }
        f32x4 o = acc * d + hv + bv;
        o.x = fmaxf(o.x, 0.f); o.y = fmaxf(o.y, 0.f);
        o.z = fmaxf(o.z, 0.f); o.w = fmaxf(o.w, 0.f);
        if (last) {
            __builtin_nontemporal_store(o, (f32x4*)&outp[(size_t)node * 128 + fl * 4]);
        } else {
            uint2 pk;
            pk.x = ((unsigned)f2bf(o.y) << 16) | f2bf(o.x);
            pk.y = ((unsigned)f2bf(o.w) << 16) | f2bf(o.z);
            *(uint2*)((char*)hb + ((size_t)node << 8) + fl * 8) = pk;
        }
    }
}

static inline size_t al256(size_t x) { return (x + 255) & ~(size_t)255; }

extern "C" void kernel_launch(void* const* d_in, const int* in_sizes, int n_in,
                              void* d_out, int out_size, void* d_ws, size_t ws_size,
                              hipStream_t stream) {
    const float* x  = (const float*)d_in[0];
    const int*   ei = (const int*)d_in[1];
    const float* Ws = (const float*)d_in[2];
    const float* bs = (const float*)d_in[3];
    int n  = in_sizes[0] / 128;          // 32768 nodes
    int E  = in_sizes[1] / 2;            // 524288 edges
    int NL = in_sizes[2] / (128 * 128);  // 3 layers
    const int* rowp = ei;
    const int* colp = ei + E;

    char* ws = (char*)d_ws;
    size_t gplane  = al256((size_t)(n + 1) * 128);   // fp8 rows, 128B
    size_t hplane  = al256((size_t)(n + 1) * 256);   // bf16 rows, 256B
    unsigned* g  = (unsigned*)ws;
    unsigned* hb = (unsigned*)(ws + gplane);
    char* p = ws + gplane + hplane;
    float* dis  = (float*)p;               p += al256((size_t)n * 4);
    int*   deg  = (int*)p;                 p += al256((size_t)n * 4);
    int*   offs = (int*)p;                 p += al256((size_t)(n + 1) * 4);
    int*   cnt  = (int*)p;                 p += al256((size_t)n * 4);
    int*   bsum = (int*)p;                 p += 512;
    ushort* csru = (ushort*)p;

    int nb = (n + 255) / 256;            // 128 scan blocks

    (void)hipMemsetAsync(deg, 0, (size_t)n * 4, stream);
    k_deg<<<(E + 255) / 256, 256, 0, stream>>>(colp, deg, E);
    k_scan1<<<nb, 256, 0, stream>>>(deg, offs, bsum, n);
    k_scan2<<<1, 128, 0, stream>>>(bsum, nb);
    k_scan3<<<nb, 256, 0, stream>>>(offs, bsum, deg, cnt, dis, g, n, E);
    k_csr<<<(E + 255) / 256, 256, 0, stream>>>(rowp, colp, cnt, csru, E);

    for (int l = 0; l < NL; ++l) {
        int last = (l + 1 == NL);
        const float* Wl = Ws + (size_t)l * 128 * 128;
        if (l == 0)
            k_gemm0<<<n / 64, 256, 0, stream>>>(x, Wl, dis, (unsigned char*)g, n);
        else
            k_gemm<<<n / 64, 256, 0, stream>>>(hb, Wl, dis, (unsigned char*)g, n);
        k_gather<<<(n + 3) / 4, 256, 0, stream>>>(g, hb, dis,
                                                  bs + (size_t)l * 128,
                                                  offs, csru, x,
                                                  (float*)d_out, n,
                                                  l == 0, last);
    }
}

// Round 10
// 150.347 us; speedup vs baseline: 1.1221x; 1.0057x over previous
//
#include <hip/hip_runtime.h>

// GCN: 3 layers, h = relu(h + GCNConv(h)), fixed graph, f32 in/out.
// g plane = raw (h@W) in fp8 e4m3, 128B rows (4MB, L2-scale). dis applied
// per-neighbor in the gather (fma). deg-atomics fused into the gemm0 launch.
// h carried bf16 (hb) between layers; layer-0 residual from f32 x.

typedef __attribute__((ext_vector_type(8))) short short8;   // 8 bf16 = 4 VGPR
typedef __attribute__((ext_vector_type(4))) float f32x4;
typedef __attribute__((ext_vector_type(2))) float f32x2;

__device__ inline ushort f2bf(float f) {           // RNE f32 -> bf16
    union { float f; unsigned u; } v; v.f = f;
    unsigned u = v.u;
    return (ushort)((u + 0x7fffu + ((u >> 16) & 1u)) >> 16);
}
__device__ inline float2 bf2f(unsigned u) {        // two packed bf16 -> float2
    union { unsigned i; float f; } a, b;
    a.i = u << 16;
    b.i = u & 0xffff0000u;
    return make_float2(a.f, b.f);
}
__device__ inline short8 pack8(f32x4 a, f32x4 b) { // 8 f32 -> short8 bf16
    short8 r = { (short)f2bf(a.x), (short)f2bf(a.y), (short)f2bf(a.z), (short)f2bf(a.w),
                 (short)f2bf(b.x), (short)f2bf(b.y), (short)f2bf(b.z), (short)f2bf(b.w) };
    return r;
}
__device__ inline unsigned char f2fp8(float f) {   // f32 -> e4m3 (HW RNE)
    return (unsigned char)(__builtin_amdgcn_cvt_pk_fp8_f32(f, f, 0, false) & 0xff);
}
__device__ inline float2 fp8x2(ushort v) {         // 2 packed e4m3 -> float2
    f32x2 lo = __builtin_amdgcn_cvt_pk_f32_fp8((int)v, false);
    return make_float2(lo.x, lo.y);
}

// ---------------- hierarchical exclusive scan ----------------
__global__ __launch_bounds__(256) void k_scan1(const int* __restrict__ deg,
                                               int* __restrict__ offs,
                                               int* __restrict__ bsum, int n) {
    __shared__ int sm[256];
    int t = threadIdx.x, i = blockIdx.x * 256 + t;
    int v = (i < n) ? deg[i] : 0;
    sm[t] = v;
    __syncthreads();
    for (int off = 1; off < 256; off <<= 1) {
        int u = (t >= off) ? sm[t - off] : 0;
        __syncthreads();
        sm[t] += u;
        __syncthreads();
    }
    if (i < n) offs[i] = sm[t] - v;
    if (t == 255) bsum[blockIdx.x] = sm[255];
}

// block-sum reduce (replaces scan2) + offs final + cnt + dis + zero g pad row
__global__ __launch_bounds__(256) void k_scan3(int* __restrict__ offs,
                                               const int* __restrict__ bsum,
                                               const int* __restrict__ deg,
                                               int* __restrict__ cnt,
                                               float* __restrict__ dis,
                                               unsigned* __restrict__ g32,
                                               int n, int E) {
    __shared__ int red[256];
    int t = threadIdx.x, bid = blockIdx.x;
    red[t] = (t < 128 && t < bid) ? bsum[t] : 0;
    __syncthreads();
    for (int off = 128; off >= 1; off >>= 1) {
        if (t < off) red[t] += red[t + off];
        __syncthreads();
    }
    int base = red[0];
    int i = bid * 256 + t;
    if (i < n) {
        int o = offs[i] + base;
        offs[i] = o;
        cnt[i] = o;
        dis[i] = rsqrtf((float)(deg[i] + 1));
    }
    if (i == 0) offs[n] = E;
    if (i < 32) g32[(size_t)n * 32 + i] = 0;  // 128B pad row
}

// ---------------- CSR build (ushort indices; order nondeterministic) ----------
__global__ void k_csr(const int* __restrict__ row, const int* __restrict__ col,
                      int* __restrict__ cnt, ushort* __restrict__ csru, int E) {
    int i = blockIdx.x * blockDim.x + threadIdx.x;
    if (i < E) {
        int c = col[i];
        int p = atomicAdd(&cnt[c], 1);
        csru[p] = (ushort)row[i];
    }
}

// ---------------- MFMA GEMM core: g = fp8(hb @ W), no dis scale ----------------
#define GEMM_BODY(A0, A1, A2, A3)                                               \
    f32x4 acc[8] = {};                                                          \
    _Pragma("unroll")                                                           \
    for (int nf = 0; nf < 8; ++nf) {                                            \
        const unsigned* wr = &Wl[nf * 16 + c][0];                               \
        int sx = (c & 7) << 2;                                                  \
        int b = q * 4;                                                          \
        short8 b0 = *(const short8*)(wr + ((b +  0) ^ sx));                     \
        short8 b1 = *(const short8*)(wr + ((b + 16) ^ sx));                     \
        short8 b2 = *(const short8*)(wr + ((b + 32) ^ sx));                     \
        short8 b3 = *(const short8*)(wr + ((b + 48) ^ sx));                     \
        acc[nf] = __builtin_amdgcn_mfma_f32_16x16x32_bf16(A0, b0, acc[nf], 0, 0, 0); \
        acc[nf] = __builtin_amdgcn_mfma_f32_16x16x32_bf16(A1, b1, acc[nf], 0, 0, 0); \
        acc[nf] = __builtin_amdgcn_mfma_f32_16x16x32_bf16(A2, b2, acc[nf], 0, 0, 0); \
        acc[nf] = __builtin_amdgcn_mfma_f32_16x16x32_bf16(A3, b3, acc[nf], 0, 0, 0); \
    }                                                                           \
    _Pragma("unroll")                                                           \
    for (int nf = 0; nf < 8; ++nf) {                                            \
        int gc = nf * 16 + c;                                                   \
        g[(size_t)(rb + q * 4 + 0) * 128 + gc] = f2fp8(acc[nf][0]);             \
        g[(size_t)(rb + q * 4 + 1) * 128 + gc] = f2fp8(acc[nf][1]);             \
        g[(size_t)(rb + q * 4 + 2) * 128 + gc] = f2fp8(acc[nf][2]);             \
        g[(size_t)(rb + q * 4 + 3) * 128 + gc] = f2fp8(acc[nf][3]);             \
    }

#define W_STAGE(TILE)                                                            \
    __shared__ unsigned Wl[128][64];                                             \
    int tid = threadIdx.x;                                                       \
    {                                                                            \
        int nn = tid & 127, hf = tid >> 7;                                       \
        for (int qq = 0; qq < 32; ++qq) {                                        \
            int k2 = hf * 32 + qq;                                               \
            float lo = W[(size_t)(2 * k2) * 128 + nn];                           \
            float hi = W[(size_t)(2 * k2 + 1) * 128 + nn];                       \
            Wl[nn][k2 ^ ((nn & 7) << 2)] = ((unsigned)f2bf(hi) << 16) | f2bf(lo);\
        }                                                                        \
    }                                                                            \
    __syncthreads();                                                             \
    int w = tid >> 6, l = tid & 63;                                              \
    int rb = (TILE) * 64 + w * 16;                                               \
    int c = l & 15, q = l >> 4;

// Layers 1..: A from bf16 hb
__global__ __launch_bounds__(256) void k_gemm(const unsigned* __restrict__ hb,
                                              const float* __restrict__ W,
                                              unsigned char* __restrict__ g, int n) {
    W_STAGE(blockIdx.x)
    const short8* arow = (const short8*)(hb + (size_t)(rb + c) * 64);
    short8 a0 = arow[q], a1 = arow[4 + q], a2 = arow[8 + q], a3 = arow[12 + q];
    GEMM_BODY(a0, a1, a2, a3)
}

// Layer 0 fused: blocks [0, n/64) do gemm0 from f32 x; remaining blocks do
// the degree atomics (independent work overlapped in one launch).
__global__ __launch_bounds__(256) void k_l0(const float* __restrict__ x,
                                            const float* __restrict__ W,
                                            unsigned char* __restrict__ g,
                                            const int* __restrict__ col,
                                            int* __restrict__ deg,
                                            int n, int E) {
    int gtiles = n >> 6;
    if ((int)blockIdx.x >= gtiles) {
        int i = ((int)blockIdx.x - gtiles) * 256 + threadIdx.x;
        if (i < E) atomicAdd(&deg[col[i]], 1);
        return;
    }
    W_STAGE((int)blockIdx.x)
    const f32x4* xr = (const f32x4*)(x + (size_t)(rb + c) * 128);
    short8 a0 = pack8(xr[q * 2 +  0], xr[q * 2 +  1]);
    short8 a1 = pack8(xr[q * 2 +  8], xr[q * 2 +  9]);
    short8 a2 = pack8(xr[q * 2 + 16], xr[q * 2 + 17]);
    short8 a3 = pack8(xr[q * 2 + 24], xr[q * 2 + 25]);
    GEMM_BODY(a0, a1, a2, a3)
}

// ---- gather: out = relu(resid + dis[c]*(sum_r g[r]*dis[r] + g[c]*dis[c]) + b) ----
// Wave per node; lane owns features 2l..2l+1 (ushort = 2 fp8 per row).
// 16 independent row loads in flight; per-neighbor dis via shfl + fma
// (pad slots have ds=0, so pad-row content is annihilated).
__global__ __launch_bounds__(256) void k_gather(const ushort* __restrict__ g,
                                                unsigned* __restrict__ hb,
                                                const float* __restrict__ dis,
                                                const float* __restrict__ bias,
                                                const int* __restrict__ offs,
                                                const ushort* __restrict__ csru,
                                                const float* __restrict__ xres,
                                                float* __restrict__ outp,
                                                int n, int use_x, int last) {
    int wid = threadIdx.x >> 6, lane = threadIdx.x & 63;
    int node = blockIdx.x * 4 + wid;
    if (node >= n) return;

    float dn = dis[node];
    float2 acc;
    {   // self-loop term: g[node]*dis[node]
        float2 f = fp8x2(g[(size_t)node * 64 + lane]);
        acc.x = f.x * dn; acc.y = f.y * dn;
    }
    int s = offs[node];
    int deg = offs[node + 1] - s;
    for (int j0 = 0; j0 < deg; j0 += 64) {
        int rem = deg - j0;
        int m = rem < 64 ? rem : 64;
        int idx = n; float dsl = 0.f;
        if (lane < m) {
            idx = (int)__builtin_nontemporal_load(&csru[s + j0 + lane]);
            dsl = dis[idx];
        }
        int mc = (m + 15) & ~15;
        for (int t = 0; t < mc; t += 16) {
            ushort v[16];
#pragma unroll
            for (int u = 0; u < 16; ++u) {
                int r = __shfl(idx, t + u, 64);
                v[u] = g[(size_t)r * 64 + lane];
            }
            float ds[16];
#pragma unroll
            for (int u = 0; u < 16; ++u) ds[u] = __shfl(dsl, t + u, 64);
#pragma unroll
            for (int u = 0; u < 16; ++u) {
                float2 f = fp8x2(v[u]);
                acc.x = fmaf(f.x, ds[u], acc.x);
                acc.y = fmaf(f.y, ds[u], acc.y);
            }
        }
    }

    float2 bv = ((const float2*)bias)[lane];
    float2 hv;
    if (use_x) {
        hv = ((const float2*)xres)[(size_t)node * 64 + lane];
    } else {
        hv = bf2f(hb[(size_t)node * 64 + lane]);
    }
    float ox = fmaxf(hv.x + acc.x * dn + bv.x, 0.f);
    float oy = fmaxf(hv.y + acc.y * dn + bv.y, 0.f);
    if (last) {
        f32x2 o = { ox, oy };
        __builtin_nontemporal_store(o, (f32x2*)&outp[(size_t)node * 128 + lane * 2]);
    } else {
        hb[(size_t)node * 64 + lane] = ((unsigned)f2bf(oy) << 16) | f2bf(ox);
    }
}

static inline size_t al256(size_t x) { return (x + 255) & ~(size_t)255; }

extern "C" void kernel_launch(void* const* d_in, const int* in_sizes, int n_in,
                              void* d_out, int out_size, void* d_ws, size_t ws_size,
                              hipStream_t stream) {
    const float* x  = (const float*)d_in[0];
    const int*   ei = (const int*)d_in[1];
    const float* Ws = (const float*)d_in[2];
    const float* bs = (const float*)d_in[3];
    int n  = in_sizes[0] / 128;          // 32768 nodes
    int E  = in_sizes[1] / 2;            // 524288 edges
    int NL = in_sizes[2] / (128 * 128);  // 3 layers
    const int* rowp = ei;
    const int* colp = ei + E;

    char* ws = (char*)d_ws;
    size_t gplane  = al256((size_t)(n + 1) * 128);   // fp8 rows, 128B
    size_t hplane  = al256((size_t)(n + 1) * 256);   // bf16 rows, 256B
    unsigned char* g  = (unsigned char*)ws;
    unsigned*      hb = (unsigned*)(ws + gplane);
    char* p = ws + gplane + hplane;
    float* dis  = (float*)p;               p += al256((size_t)n * 4);
    int*   deg  = (int*)p;                 p += al256((size_t)n * 4);
    int*   offs = (int*)p;                 p += al256((size_t)(n + 1) * 4);
    int*   cnt  = (int*)p;                 p += al256((size_t)n * 4);
    int*   bsum = (int*)p;                 p += 512;
    ushort* csru = (ushort*)p;

    int nb = (n + 255) / 256;            // 128 scan blocks
    int gtiles = n / 64;                 // 512
    int eblocks = (E + 255) / 256;       // 2048

    (void)hipMemsetAsync(deg, 0, (size_t)n * 4, stream);
    // gemm0 (raw h@W -> fp8 g) overlapped with degree atomics
    k_l0<<<gtiles + eblocks, 256, 0, stream>>>(x, Ws, g, colp, deg, n, E);
    k_scan1<<<nb, 256, 0, stream>>>(deg, offs, bsum, n);
    k_scan3<<<nb, 256, 0, stream>>>(offs, bsum, deg, cnt, dis, (unsigned*)g, n, E);
    k_csr<<<eblocks, 256, 0, stream>>>(rowp, colp, cnt, csru, E);

    for (int l = 0; l < NL; ++l) {
        int last = (l + 1 == NL);
        if (l > 0)
            k_gemm<<<gtiles, 256, 0, stream>>>(hb, Ws + (size_t)l * 128 * 128,
                                               g, n);
        k_gather<<<(n + 3) / 4, 256, 0, stream>>>((const ushort*)g, hb, dis,
                                                  bs + (size_t)l * 128,
                                                  offs, csru, x,
                                                  (float*)d_out, n,
                                                  l == 0, last);
    }
}

// Round 11
// 142.315 us; speedup vs baseline: 1.1854x; 1.0564x over previous
//
#include <hip/hip_runtime.h>

// GCN: 3 layers, h = relu(h + GCNConv(h)), fixed graph, f32 in/out.
// g plane = fp8 e4m3 rows (128B) PRE-SCALED by dis[row] -> gather does pure
// row-sum (no per-neighbor dis transactions). 2 nodes/wave (32-lane halves).
// h carried bf16 (hb); layer-0 residual from f32 x; deg fused into gemm0.

typedef __attribute__((ext_vector_type(8))) short short8;   // 8 bf16 = 4 VGPR
typedef __attribute__((ext_vector_type(4))) float f32x4;
typedef __attribute__((ext_vector_type(2))) float f32x2;
typedef __attribute__((ext_vector_type(2))) unsigned u32x2;

__device__ inline ushort f2bf(float f) {           // RNE f32 -> bf16
    union { float f; unsigned u; } v; v.f = f;
    unsigned u = v.u;
    return (ushort)((u + 0x7fffu + ((u >> 16) & 1u)) >> 16);
}
__device__ inline float2 bf2f(unsigned u) {        // two packed bf16 -> float2
    union { unsigned i; float f; } a, b;
    a.i = u << 16;
    b.i = u & 0xffff0000u;
    return make_float2(a.f, b.f);
}
__device__ inline f32x4 bf4(u32x2 v) {             // 4 packed bf16 -> f32x4
    float2 a = bf2f(v.x), b = bf2f(v.y);
    f32x4 r = { a.x, a.y, b.x, b.y };
    return r;
}
__device__ inline short8 pack8(f32x4 a, f32x4 b) { // 8 f32 -> short8 bf16
    short8 r = { (short)f2bf(a.x), (short)f2bf(a.y), (short)f2bf(a.z), (short)f2bf(a.w),
                 (short)f2bf(b.x), (short)f2bf(b.y), (short)f2bf(b.z), (short)f2bf(b.w) };
    return r;
}
__device__ inline unsigned char f2fp8(float f) {   // f32 -> e4m3 (HW RNE)
    return (unsigned char)(__builtin_amdgcn_cvt_pk_fp8_f32(f, f, 0, false) & 0xff);
}
__device__ inline unsigned pack4fp8(f32x4 v) {     // 4 f32 -> 4 packed e4m3
    unsigned u = (unsigned)__builtin_amdgcn_cvt_pk_fp8_f32(v.x, v.y, 0, false);
    u = (unsigned)__builtin_amdgcn_cvt_pk_fp8_f32(v.z, v.w, (int)u, true);
    return u;
}
__device__ inline f32x4 fp8x4(unsigned v) {        // 4 packed e4m3 -> f32x4
    f32x2 lo = __builtin_amdgcn_cvt_pk_f32_fp8((int)v, false);
    f32x2 hi = __builtin_amdgcn_cvt_pk_f32_fp8((int)v, true);
    f32x4 r = { lo.x, lo.y, hi.x, hi.y };
    return r;
}

// ---------------- hierarchical exclusive scan ----------------
__global__ __launch_bounds__(256) void k_scan1(const int* __restrict__ deg,
                                               int* __restrict__ offs,
                                               int* __restrict__ bsum, int n) {
    __shared__ int sm[256];
    int t = threadIdx.x, i = blockIdx.x * 256 + t;
    int v = (i < n) ? deg[i] : 0;
    sm[t] = v;
    __syncthreads();
    for (int off = 1; off < 256; off <<= 1) {
        int u = (t >= off) ? sm[t - off] : 0;
        __syncthreads();
        sm[t] += u;
        __syncthreads();
    }
    if (i < n) offs[i] = sm[t] - v;
    if (t == 255) bsum[blockIdx.x] = sm[255];
}

// block-sum reduce + offs final + cnt + dis + zero pad row + RESCALE layer-0 g
__global__ __launch_bounds__(256) void k_scan3(int* __restrict__ offs,
                                               const int* __restrict__ bsum,
                                               const int* __restrict__ deg,
                                               int* __restrict__ cnt,
                                               float* __restrict__ dis,
                                               unsigned* __restrict__ g32,
                                               int n, int E) {
    __shared__ int red[256];
    int t = threadIdx.x, bid = blockIdx.x;
    red[t] = (t < 128 && t < bid) ? bsum[t] : 0;
    __syncthreads();
    for (int off = 128; off >= 1; off >>= 1) {
        if (t < off) red[t] += red[t + off];
        __syncthreads();
    }
    int base = red[0];
    int i = bid * 256 + t;
    float dv = 0.f;
    if (i < n) {
        int o = offs[i] + base;
        offs[i] = o;
        cnt[i] = o;
        dv = rsqrtf((float)(deg[i] + 1));
        dis[i] = dv;
    }
    if (i == 0) offs[n] = E;
    if (i < 32) g32[(size_t)n * 32 + i] = 0;  // 128B pad row stays zero

    // in-place rescale of this wave's 64 g rows by dis (coalesced, 2 rows/iter)
    int lane = t & 63;
    int wbase = bid * 256 + (t & ~63);
    int hl = lane & 31, sel = lane >> 5;
    for (int rr = 0; rr < 64; rr += 2) {
        int row = wbase + rr + sel;
        float d = __shfl(dv, rr + sel, 64);
        if (row < n) {
            unsigned u = g32[(size_t)row * 32 + hl];
            g32[(size_t)row * 32 + hl] = pack4fp8(fp8x4(u) * d);
        }
    }
}

// ---------------- CSR build (ushort indices; order nondeterministic) ----------
__global__ void k_csr(const int* __restrict__ row, const int* __restrict__ col,
                      int* __restrict__ cnt, ushort* __restrict__ csru, int E) {
    int i = blockIdx.x * blockDim.x + threadIdx.x;
    if (i < E) {
        int c = col[i];
        int p = atomicAdd(&cnt[c], 1);
        csru[p] = (ushort)row[i];
    }
}

// ---------------- MFMA GEMM core ----------------
#define GEMM_MAIN(A0, A1, A2, A3)                                               \
    f32x4 acc[8] = {};                                                          \
    _Pragma("unroll")                                                           \
    for (int nf = 0; nf < 8; ++nf) {                                            \
        const unsigned* wr = &Wl[nf * 16 + c][0];                               \
        int sx = (c & 7) << 2;                                                  \
        int b = q * 4;                                                          \
        short8 b0 = *(const short8*)(wr + ((b +  0) ^ sx));                     \
        short8 b1 = *(const short8*)(wr + ((b + 16) ^ sx));                     \
        short8 b2 = *(const short8*)(wr + ((b + 32) ^ sx));                     \
        short8 b3 = *(const short8*)(wr + ((b + 48) ^ sx));                     \
        acc[nf] = __builtin_amdgcn_mfma_f32_16x16x32_bf16(A0, b0, acc[nf], 0, 0, 0); \
        acc[nf] = __builtin_amdgcn_mfma_f32_16x16x32_bf16(A1, b1, acc[nf], 0, 0, 0); \
        acc[nf] = __builtin_amdgcn_mfma_f32_16x16x32_bf16(A2, b2, acc[nf], 0, 0, 0); \
        acc[nf] = __builtin_amdgcn_mfma_f32_16x16x32_bf16(A3, b3, acc[nf], 0, 0, 0); \
    }

#define GEMM_STORE(D0, D1, D2, D3)                                              \
    _Pragma("unroll")                                                           \
    for (int nf = 0; nf < 8; ++nf) {                                            \
        int gc = nf * 16 + c;                                                   \
        g[(size_t)(rb + q * 4 + 0) * 128 + gc] = f2fp8(acc[nf][0] * (D0));      \
        g[(size_t)(rb + q * 4 + 1) * 128 + gc] = f2fp8(acc[nf][1] * (D1));      \
        g[(size_t)(rb + q * 4 + 2) * 128 + gc] = f2fp8(acc[nf][2] * (D2));      \
        g[(size_t)(rb + q * 4 + 3) * 128 + gc] = f2fp8(acc[nf][3] * (D3));      \
    }

#define W_STAGE(TILE)                                                            \
    __shared__ unsigned Wl[128][64];                                             \
    int tid = threadIdx.x;                                                       \
    {                                                                            \
        int nn = tid & 127, hf = tid >> 7;                                       \
        for (int qq = 0; qq < 32; ++qq) {                                        \
            int k2 = hf * 32 + qq;                                               \
            float lo = W[(size_t)(2 * k2) * 128 + nn];                           \
            float hi = W[(size_t)(2 * k2 + 1) * 128 + nn];                       \
            Wl[nn][k2 ^ ((nn & 7) << 2)] = ((unsigned)f2bf(hi) << 16) | f2bf(lo);\
        }                                                                        \
    }                                                                            \
    __syncthreads();                                                             \
    int w = tid >> 6, l = tid & 63;                                              \
    int rb = (TILE) * 64 + w * 16;                                               \
    int c = l & 15, q = l >> 4;

// Layers 1..: A from bf16 hb; dis applied at epilogue (pre-scaled g rows)
__global__ __launch_bounds__(256) void k_gemm(const unsigned* __restrict__ hb,
                                              const float* __restrict__ W,
                                              const float* __restrict__ dis,
                                              unsigned char* __restrict__ g, int n) {
    W_STAGE(blockIdx.x)
    const short8* arow = (const short8*)(hb + (size_t)(rb + c) * 64);
    short8 a0 = arow[q], a1 = arow[4 + q], a2 = arow[8 + q], a3 = arow[12 + q];
    GEMM_MAIN(a0, a1, a2, a3)
    float d0 = dis[rb + q * 4 + 0], d1 = dis[rb + q * 4 + 1];
    float d2 = dis[rb + q * 4 + 2], d3 = dis[rb + q * 4 + 3];
    GEMM_STORE(d0, d1, d2, d3)
}

// Layer 0 fused: blocks [0, n/64) do raw gemm0 from f32 x (dis not yet known;
// scan3 rescales in place); remaining blocks do the degree atomics.
__global__ __launch_bounds__(256) void k_l0(const float* __restrict__ x,
                                            const float* __restrict__ W,
                                            unsigned char* __restrict__ g,
                                            const int* __restrict__ col,
                                            int* __restrict__ deg,
                                            int n, int E) {
    int gtiles = n >> 6;
    if ((int)blockIdx.x >= gtiles) {
        int i = ((int)blockIdx.x - gtiles) * 256 + threadIdx.x;
        if (i < E) atomicAdd(&deg[col[i]], 1);
        return;
    }
    W_STAGE((int)blockIdx.x)
    const f32x4* xr = (const f32x4*)(x + (size_t)(rb + c) * 128);
    short8 a0 = pack8(xr[q * 2 +  0], xr[q * 2 +  1]);
    short8 a1 = pack8(xr[q * 2 +  8], xr[q * 2 +  9]);
    short8 a2 = pack8(xr[q * 2 + 16], xr[q * 2 + 17]);
    short8 a3 = pack8(xr[q * 2 + 24], xr[q * 2 + 25]);
    GEMM_MAIN(a0, a1, a2, a3)
    GEMM_STORE(1.f, 1.f, 1.f, 1.f)
}

// ---- gather: out = relu(resid + dis[c]*(g[c] + sum g[nbr]) + b), g pre-scaled --
// 2 nodes per wave (32-lane halves). Per neighbor: one uint (4 fp8) per lane,
// 128B/row transaction. 16 rows in flight per half (32/wave). Zero pad row
// absorbs the tail. NT hints on all streaming accesses; g stays cached.
__global__ __launch_bounds__(256) void k_gather(const unsigned* __restrict__ g32,
                                                unsigned* __restrict__ hb,
                                                const float* __restrict__ dis,
                                                const float* __restrict__ bias,
                                                const int* __restrict__ offs,
                                                const ushort* __restrict__ csru,
                                                const float* __restrict__ xres,
                                                float* __restrict__ outp,
                                                int n, int use_x, int last) {
    int wid = threadIdx.x >> 6, lane = threadIdx.x & 63;
    int sel = lane >> 5, hl = lane & 31;
    int node = blockIdx.x * 8 + wid * 2 + sel;
    if (node >= n) return;

    f32x4 acc = fp8x4(g32[(size_t)node * 32 + hl]);   // self-loop (pre-scaled)
    int s = offs[node];
    int deg = offs[node + 1] - s;
    for (int j0 = 0; j0 < deg; j0 += 32) {
        int rem = deg - j0;
        int m = rem < 32 ? rem : 32;
        int idx = (hl < m) ? (int)__builtin_nontemporal_load(&csru[s + j0 + hl]) : n;
        int mc = (m + 15) & ~15;
        for (int t = 0; t < mc; t += 16) {
            unsigned v[16];
#pragma unroll
            for (int u = 0; u < 16; ++u) {
                int r = __shfl(idx, t + u, 32);
                v[u] = g32[(size_t)r * 32 + hl];
            }
            f32x4 s0 = (fp8x4(v[0]) + fp8x4(v[1])) + (fp8x4(v[2]) + fp8x4(v[3]));
            f32x4 s1 = (fp8x4(v[4]) + fp8x4(v[5])) + (fp8x4(v[6]) + fp8x4(v[7]));
            f32x4 s2 = (fp8x4(v[8]) + fp8x4(v[9])) + (fp8x4(v[10]) + fp8x4(v[11]));
            f32x4 s3 = (fp8x4(v[12]) + fp8x4(v[13])) + (fp8x4(v[14]) + fp8x4(v[15]));
            acc += (s0 + s1) + (s2 + s3);
        }
    }
    float dn = dis[node];
    f32x4 bv = ((const f32x4*)bias)[hl];
    f32x4 hv;
    if (use_x) {
        hv = __builtin_nontemporal_load(&((const f32x4*)xres)[(size_t)node * 32 + hl]);
    } else {
        u32x2 h2 = __builtin_nontemporal_load(&((const u32x2*)hb)[(size_t)node * 32 + hl]);
        hv = bf4(h2);
    }
    f32x4 o = acc * dn + hv + bv;
    o.x = fmaxf(o.x, 0.f); o.y = fmaxf(o.y, 0.f);
    o.z = fmaxf(o.z, 0.f); o.w = fmaxf(o.w, 0.f);
    if (last) {
        __builtin_nontemporal_store(o, &((f32x4*)outp)[(size_t)node * 32 + hl]);
    } else {
        u32x2 pk;
        pk.x = ((unsigned)f2bf(o.y) << 16) | f2bf(o.x);
        pk.y = ((unsigned)f2bf(o.w) << 16) | f2bf(o.z);
        __builtin_nontemporal_store(pk, &((u32x2*)hb)[(size_t)node * 32 + hl]);
    }
}

static inline size_t al256(size_t x) { return (x + 255) & ~(size_t)255; }

extern "C" void kernel_launch(void* const* d_in, const int* in_sizes, int n_in,
                              void* d_out, int out_size, void* d_ws, size_t ws_size,
                              hipStream_t stream) {
    const float* x  = (const float*)d_in[0];
    const int*   ei = (const int*)d_in[1];
    const float* Ws = (const float*)d_in[2];
    const float* bs = (const float*)d_in[3];
    int n  = in_sizes[0] / 128;          // 32768 nodes
    int E  = in_sizes[1] / 2;            // 524288 edges
    int NL = in_sizes[2] / (128 * 128);  // 3 layers
    const int* rowp = ei;
    const int* colp = ei + E;

    char* ws = (char*)d_ws;
    size_t gplane  = al256((size_t)(n + 1) * 128);   // fp8 rows, 128B
    size_t hplane  = al256((size_t)(n + 1) * 256);   // bf16 rows, 256B
    unsigned char* g  = (unsigned char*)ws;
    unsigned*      hb = (unsigned*)(ws + gplane);
    char* p = ws + gplane + hplane;
    float* dis  = (float*)p;               p += al256((size_t)n * 4);
    int*   deg  = (int*)p;                 p += al256((size_t)n * 4);
    int*   offs = (int*)p;                 p += al256((size_t)(n + 1) * 4);
    int*   cnt  = (int*)p;                 p += al256((size_t)n * 4);
    int*   bsum = (int*)p;                 p += 512;
    ushort* csru = (ushort*)p;

    int nb = (n + 255) / 256;            // 128 scan blocks
    int gtiles = n / 64;                 // 512
    int eblocks = (E + 255) / 256;       // 2048

    (void)hipMemsetAsync(deg, 0, (size_t)n * 4, stream);
    k_l0<<<gtiles + eblocks, 256, 0, stream>>>(x, Ws, g, colp, deg, n, E);
    k_scan1<<<nb, 256, 0, stream>>>(deg, offs, bsum, n);
    k_scan3<<<nb, 256, 0, stream>>>(offs, bsum, deg, cnt, dis, (unsigned*)g, n, E);
    k_csr<<<eblocks, 256, 0, stream>>>(rowp, colp, cnt, csru, E);

    for (int l = 0; l < NL; ++l) {
        int last = (l + 1 == NL);
        if (l > 0)
            k_gemm<<<gtiles, 256, 0, stream>>>(hb, Ws + (size_t)l * 128 * 128,
                                               dis, g, n);
        k_gather<<<(n + 7) / 8, 256, 0, stream>>>((const unsigned*)g, hb, dis,
                                                  bs + (size_t)l * 128,
                                                  offs, csru, x,
                                                  (float*)d_out, n,
                                                  l == 0, last);
    }
}

// Round 12
// 136.839 us; speedup vs baseline: 1.2329x; 1.0400x over previous
//
#include <hip/hip_runtime.h>

// GCN: 3 layers, h = relu(h + GCNConv(h)), fixed graph, f32 in/out.
// g plane = fp8 e4m3 rows (128B) pre-scaled by dis[row]; gather = pure row-sum,
// 2 nodes/wave, up to 32 rows in flight, 8-granular tail via zero pad row.
// Setup: memset -> deg -> scan1 -> scan3 -> [gemm0(dis) || csr] fused launch.

typedef __attribute__((ext_vector_type(8))) short short8;   // 8 bf16 = 4 VGPR
typedef __attribute__((ext_vector_type(4))) float f32x4;
typedef __attribute__((ext_vector_type(2))) float f32x2;
typedef __attribute__((ext_vector_type(2))) unsigned u32x2;

__device__ inline ushort f2bf(float f) {           // RNE f32 -> bf16
    union { float f; unsigned u; } v; v.f = f;
    unsigned u = v.u;
    return (ushort)((u + 0x7fffu + ((u >> 16) & 1u)) >> 16);
}
__device__ inline float2 bf2f(unsigned u) {        // two packed bf16 -> float2
    union { unsigned i; float f; } a, b;
    a.i = u << 16;
    b.i = u & 0xffff0000u;
    return make_float2(a.f, b.f);
}
__device__ inline f32x4 bf4(u32x2 v) {             // 4 packed bf16 -> f32x4
    float2 a = bf2f(v.x), b = bf2f(v.y);
    f32x4 r = { a.x, a.y, b.x, b.y };
    return r;
}
__device__ inline short8 pack8(f32x4 a, f32x4 b) { // 8 f32 -> short8 bf16
    short8 r = { (short)f2bf(a.x), (short)f2bf(a.y), (short)f2bf(a.z), (short)f2bf(a.w),
                 (short)f2bf(b.x), (short)f2bf(b.y), (short)f2bf(b.z), (short)f2bf(b.w) };
    return r;
}
__device__ inline unsigned char f2fp8(float f) {   // f32 -> e4m3 (HW RNE)
    return (unsigned char)(__builtin_amdgcn_cvt_pk_fp8_f32(f, f, 0, false) & 0xff);
}
__device__ inline f32x4 fp8x4(unsigned v) {        // 4 packed e4m3 -> f32x4
    f32x2 lo = __builtin_amdgcn_cvt_pk_f32_fp8((int)v, false);
    f32x2 hi = __builtin_amdgcn_cvt_pk_f32_fp8((int)v, true);
    f32x4 r = { lo.x, lo.y, hi.x, hi.y };
    return r;
}

// ---------------- degree ----------------
__global__ void k_deg(const int* __restrict__ col, int* __restrict__ deg, int E) {
    int i = blockIdx.x * blockDim.x + threadIdx.x;
    if (i < E) atomicAdd(&deg[col[i]], 1);
}

// ---------------- hierarchical exclusive scan ----------------
__global__ __launch_bounds__(256) void k_scan1(const int* __restrict__ deg,
                                               int* __restrict__ offs,
                                               int* __restrict__ bsum, int n) {
    __shared__ int sm[256];
    int t = threadIdx.x, i = blockIdx.x * 256 + t;
    int v = (i < n) ? deg[i] : 0;
    sm[t] = v;
    __syncthreads();
    for (int off = 1; off < 256; off <<= 1) {
        int u = (t >= off) ? sm[t - off] : 0;
        __syncthreads();
        sm[t] += u;
        __syncthreads();
    }
    if (i < n) offs[i] = sm[t] - v;
    if (t == 255) bsum[blockIdx.x] = sm[255];
}

// block-sum reduce + offs final + cnt + dis + zero g pad row
__global__ __launch_bounds__(256) void k_scan3(int* __restrict__ offs,
                                               const int* __restrict__ bsum,
                                               const int* __restrict__ deg,
                                               int* __restrict__ cnt,
                                               float* __restrict__ dis,
                                               unsigned* __restrict__ g32,
                                               int n, int E) {
    __shared__ int red[256];
    int t = threadIdx.x, bid = blockIdx.x;
    red[t] = (t < 128 && t < bid) ? bsum[t] : 0;
    __syncthreads();
    for (int off = 128; off >= 1; off >>= 1) {
        if (t < off) red[t] += red[t + off];
        __syncthreads();
    }
    int base = red[0];
    int i = bid * 256 + t;
    if (i < n) {
        int o = offs[i] + base;
        offs[i] = o;
        cnt[i] = o;
        dis[i] = rsqrtf((float)(deg[i] + 1));
    }
    if (i == 0) offs[n] = E;
    if (i < 32) g32[(size_t)n * 32 + i] = 0;  // 128B pad row
}

// ---------------- MFMA GEMM core ----------------
#define GEMM_MAIN(A0, A1, A2, A3)                                               \
    f32x4 acc[8] = {};                                                          \
    _Pragma("unroll")                                                           \
    for (int nf = 0; nf < 8; ++nf) {                                            \
        const unsigned* wr = &Wl[nf * 16 + c][0];                               \
        int sx = (c & 7) << 2;                                                  \
        int b = q * 4;                                                          \
        short8 b0 = *(const short8*)(wr + ((b +  0) ^ sx));                     \
        short8 b1 = *(const short8*)(wr + ((b + 16) ^ sx));                     \
        short8 b2 = *(const short8*)(wr + ((b + 32) ^ sx));                     \
        short8 b3 = *(const short8*)(wr + ((b + 48) ^ sx));                     \
        acc[nf] = __builtin_amdgcn_mfma_f32_16x16x32_bf16(A0, b0, acc[nf], 0, 0, 0); \
        acc[nf] = __builtin_amdgcn_mfma_f32_16x16x32_bf16(A1, b1, acc[nf], 0, 0, 0); \
        acc[nf] = __builtin_amdgcn_mfma_f32_16x16x32_bf16(A2, b2, acc[nf], 0, 0, 0); \
        acc[nf] = __builtin_amdgcn_mfma_f32_16x16x32_bf16(A3, b3, acc[nf], 0, 0, 0); \
    }

#define GEMM_STORE(D0, D1, D2, D3)                                              \
    _Pragma("unroll")                                                           \
    for (int nf = 0; nf < 8; ++nf) {                                            \
        int gc = nf * 16 + c;                                                   \
        g[(size_t)(rb + q * 4 + 0) * 128 + gc] = f2fp8(acc[nf][0] * (D0));      \
        g[(size_t)(rb + q * 4 + 1) * 128 + gc] = f2fp8(acc[nf][1] * (D1));      \
        g[(size_t)(rb + q * 4 + 2) * 128 + gc] = f2fp8(acc[nf][2] * (D2));      \
        g[(size_t)(rb + q * 4 + 3) * 128 + gc] = f2fp8(acc[nf][3] * (D3));      \
    }

#define W_STAGE(TILE)                                                            \
    __shared__ unsigned Wl[128][64];                                             \
    int tid = threadIdx.x;                                                       \
    {                                                                            \
        int nn = tid & 127, hf = tid >> 7;                                       \
        for (int qq = 0; qq < 32; ++qq) {                                        \
            int k2 = hf * 32 + qq;                                               \
            float lo = W[(size_t)(2 * k2) * 128 + nn];                           \
            float hi = W[(size_t)(2 * k2 + 1) * 128 + nn];                       \
            Wl[nn][k2 ^ ((nn & 7) << 2)] = ((unsigned)f2bf(hi) << 16) | f2bf(lo);\
        }                                                                        \
    }                                                                            \
    __syncthreads();                                                             \
    int w = tid >> 6, l = tid & 63;                                              \
    int rb = (TILE) * 64 + w * 16;                                               \
    int c = l & 15, q = l >> 4;

// Layers 1..: A from bf16 hb; dis applied at epilogue (pre-scaled g rows)
__global__ __launch_bounds__(256) void k_gemm(const unsigned* __restrict__ hb,
                                              const float* __restrict__ W,
                                              const float* __restrict__ dis,
                                              unsigned char* __restrict__ g, int n) {
    W_STAGE(blockIdx.x)
    const short8* arow = (const short8*)(hb + (size_t)(rb + c) * 64);
    short8 a0 = __builtin_nontemporal_load(&arow[q]);
    short8 a1 = __builtin_nontemporal_load(&arow[4 + q]);
    short8 a2 = __builtin_nontemporal_load(&arow[8 + q]);
    short8 a3 = __builtin_nontemporal_load(&arow[12 + q]);
    GEMM_MAIN(a0, a1, a2, a3)
    float d0 = dis[rb + q * 4 + 0], d1 = dis[rb + q * 4 + 1];
    float d2 = dis[rb + q * 4 + 2], d3 = dis[rb + q * 4 + 3];
    GEMM_STORE(d0, d1, d2, d3)
}

// Fused: blocks [0, n/64) = gemm0 from f32 x with dis epilogue;
// blocks [n/64, ...) = CSR build (independent, overlapped).
__global__ __launch_bounds__(256) void k_l0b(const float* __restrict__ x,
                                             const float* __restrict__ W,
                                             const float* __restrict__ dis,
                                             unsigned char* __restrict__ g,
                                             const int* __restrict__ rowp,
                                             const int* __restrict__ colp,
                                             int* __restrict__ cnt,
                                             ushort* __restrict__ csru,
                                             int n, int E) {
    int gtiles = n >> 6;
    if ((int)blockIdx.x >= gtiles) {
        int i = ((int)blockIdx.x - gtiles) * 256 + threadIdx.x;
        if (i < E) {
            int cc = colp[i];
            int p = atomicAdd(&cnt[cc], 1);
            csru[p] = (ushort)rowp[i];
        }
        return;
    }
    W_STAGE((int)blockIdx.x)
    const f32x4* xr = (const f32x4*)(x + (size_t)(rb + c) * 128);
    short8 a0 = pack8(xr[q * 2 +  0], xr[q * 2 +  1]);
    short8 a1 = pack8(xr[q * 2 +  8], xr[q * 2 +  9]);
    short8 a2 = pack8(xr[q * 2 + 16], xr[q * 2 + 17]);
    short8 a3 = pack8(xr[q * 2 + 24], xr[q * 2 + 25]);
    GEMM_MAIN(a0, a1, a2, a3)
    float d0 = dis[rb + q * 4 + 0], d1 = dis[rb + q * 4 + 1];
    float d2 = dis[rb + q * 4 + 2], d3 = dis[rb + q * 4 + 3];
    GEMM_STORE(d0, d1, d2, d3)
}

// ---- gather: out = relu(resid + dis[c]*(g[c] + sum g[nbr]) + b), g pre-scaled --
// 2 nodes/wave (32-lane halves), 4B/lane/row. Whole <=32-row chunk issued
// before accumulation (static v[32] stays in registers); tail rounded to 8
// with zero pad row absorbing <=7 slots. Epilogue operands prefetched.
__global__ __launch_bounds__(256) void k_gather(const unsigned* __restrict__ g32,
                                                unsigned* __restrict__ hb,
                                                const float* __restrict__ dis,
                                                const float* __restrict__ bias,
                                                const int* __restrict__ offs,
                                                const ushort* __restrict__ csru,
                                                const float* __restrict__ xres,
                                                float* __restrict__ outp,
                                                int n, int use_x, int last) {
    int wid = threadIdx.x >> 6, lane = threadIdx.x & 63;
    int sel = lane >> 5, hl = lane & 31;
    int node = blockIdx.x * 8 + wid * 2 + sel;
    if (node >= n) return;

    // prefetch epilogue operands (latency hides under the neighbor loop)
    float dn = dis[node];
    f32x4 bv = ((const f32x4*)bias)[hl];
    f32x4 hv;
    if (use_x) {
        hv = __builtin_nontemporal_load(&((const f32x4*)xres)[(size_t)node * 32 + hl]);
    } else {
        u32x2 h2 = __builtin_nontemporal_load(&((const u32x2*)hb)[(size_t)node * 32 + hl]);
        hv = bf4(h2);
    }

    f32x4 acc = fp8x4(g32[(size_t)node * 32 + hl]);   // self-loop (pre-scaled)
    int s = offs[node];
    int deg = offs[node + 1] - s;
    for (int j0 = 0; j0 < deg; j0 += 32) {
        int rem = deg - j0;
        int m = rem < 32 ? rem : 32;
        int idx = (hl < m) ? (int)__builtin_nontemporal_load(&csru[s + j0 + hl]) : n;
        int mc = (m + 7) & ~7;
        unsigned v[32];
#pragma unroll
        for (int b = 0; b < 4; ++b) {
            if (b * 8 < mc) {
#pragma unroll
                for (int u = 0; u < 8; ++u) {
                    int r = __shfl(idx, b * 8 + u, 32);
                    v[b * 8 + u] = g32[(size_t)r * 32 + hl];
                }
            }
        }
#pragma unroll
        for (int b = 0; b < 4; ++b) {
            if (b * 8 < mc) {
                f32x4 s0 = (fp8x4(v[b * 8 + 0]) + fp8x4(v[b * 8 + 1])) +
                           (fp8x4(v[b * 8 + 2]) + fp8x4(v[b * 8 + 3]));
                f32x4 s1 = (fp8x4(v[b * 8 + 4]) + fp8x4(v[b * 8 + 5])) +
                           (fp8x4(v[b * 8 + 6]) + fp8x4(v[b * 8 + 7]));
                acc += s0 + s1;
            }
        }
    }

    f32x4 o = acc * dn + hv + bv;
    o.x = fmaxf(o.x, 0.f); o.y = fmaxf(o.y, 0.f);
    o.z = fmaxf(o.z, 0.f); o.w = fmaxf(o.w, 0.f);
    if (last) {
        __builtin_nontemporal_store(o, &((f32x4*)outp)[(size_t)node * 32 + hl]);
    } else {
        u32x2 pk;
        pk.x = ((unsigned)f2bf(o.y) << 16) | f2bf(o.x);
        pk.y = ((unsigned)f2bf(o.w) << 16) | f2bf(o.z);
        __builtin_nontemporal_store(pk, &((u32x2*)hb)[(size_t)node * 32 + hl]);
    }
}

static inline size_t al256(size_t x) { return (x + 255) & ~(size_t)255; }

extern "C" void kernel_launch(void* const* d_in, const int* in_sizes, int n_in,
                              void* d_out, int out_size, void* d_ws, size_t ws_size,
                              hipStream_t stream) {
    const float* x  = (const float*)d_in[0];
    const int*   ei = (const int*)d_in[1];
    const float* Ws = (const float*)d_in[2];
    const float* bs = (const float*)d_in[3];
    int n  = in_sizes[0] / 128;          // 32768 nodes
    int E  = in_sizes[1] / 2;            // 524288 edges
    int NL = in_sizes[2] / (128 * 128);  // 3 layers
    const int* rowp = ei;
    const int* colp = ei + E;

    char* ws = (char*)d_ws;
    size_t gplane  = al256((size_t)(n + 1) * 128);   // fp8 rows, 128B
    size_t hplane  = al256((size_t)(n + 1) * 256);   // bf16 rows, 256B
    unsigned char* g  = (unsigned char*)ws;
    unsigned*      hb = (unsigned*)(ws + gplane);
    char* p = ws + gplane + hplane;
    float* dis  = (float*)p;               p += al256((size_t)n * 4);
    int*   deg  = (int*)p;                 p += al256((size_t)n * 4);
    int*   offs = (int*)p;                 p += al256((size_t)(n + 1) * 4);
    int*   cnt  = (int*)p;                 p += al256((size_t)n * 4);
    int*   bsum = (int*)p;                 p += 512;
    ushort* csru = (ushort*)p;

    int nb = (n + 255) / 256;            // 128 scan blocks
    int gtiles = n / 64;                 // 512
    int eblocks = (E + 255) / 256;       // 2048

    (void)hipMemsetAsync(deg, 0, (size_t)n * 4, stream);
    k_deg<<<eblocks, 256, 0, stream>>>(colp, deg, E);
    k_scan1<<<nb, 256, 0, stream>>>(deg, offs, bsum, n);
    k_scan3<<<nb, 256, 0, stream>>>(offs, bsum, deg, cnt, dis, (unsigned*)g, n, E);
    // gemm0 (with dis epilogue) overlapped with CSR build
    k_l0b<<<gtiles + eblocks, 256, 0, stream>>>(x, Ws, dis, g, rowp, colp,
                                                cnt, csru, n, E);

    for (int l = 0; l < NL; ++l) {
        int last = (l + 1 == NL);
        if (l > 0)
            k_gemm<<<gtiles, 256, 0, stream>>>(hb, Ws + (size_t)l * 128 * 128,
                                               dis, g, n);
        k_gather<<<(n + 7) / 8, 256, 0, stream>>>((const unsigned*)g, hb, dis,
                                                  bs + (size_t)l * 128,
                                                  offs, csru, x,
                                                  (float*)d_out, n,
                                                  l == 0, last);
    }
}

// Round 13
// 136.675 us; speedup vs baseline: 1.2344x; 1.0012x over previous
//
#include <hip/hip_runtime.h>

// GCN: 3 layers, h = relu(h + GCNConv(h)), fixed graph, f32 in/out.
// g plane = fp8 e4m3 rows (128B) pre-scaled by dis[row]; gather = pure row-sum,
// 2 nodes/wave, up to 32 rows in flight, 8-granular tail via zero pad row.
// Setup: k_zero -> deg -> scan1 -> scan3 -> [gemm0(dis) || csr] fused launch.
// NOTE: hipMemsetAsync's small-fill kernel ran at ~3 GB/s (43us for 128KB,
// seen in rocprof) -- replaced with a plain store kernel.

typedef __attribute__((ext_vector_type(8))) short short8;   // 8 bf16 = 4 VGPR
typedef __attribute__((ext_vector_type(4))) float f32x4;
typedef __attribute__((ext_vector_type(2))) float f32x2;
typedef __attribute__((ext_vector_type(2))) unsigned u32x2;

__device__ inline ushort f2bf(float f) {           // RNE f32 -> bf16
    union { float f; unsigned u; } v; v.f = f;
    unsigned u = v.u;
    return (ushort)((u + 0x7fffu + ((u >> 16) & 1u)) >> 16);
}
__device__ inline float2 bf2f(unsigned u) {        // two packed bf16 -> float2
    union { unsigned i; float f; } a, b;
    a.i = u << 16;
    b.i = u & 0xffff0000u;
    return make_float2(a.f, b.f);
}
__device__ inline f32x4 bf4(u32x2 v) {             // 4 packed bf16 -> f32x4
    float2 a = bf2f(v.x), b = bf2f(v.y);
    f32x4 r = { a.x, a.y, b.x, b.y };
    return r;
}
__device__ inline short8 pack8(f32x4 a, f32x4 b) { // 8 f32 -> short8 bf16
    short8 r = { (short)f2bf(a.x), (short)f2bf(a.y), (short)f2bf(a.z), (short)f2bf(a.w),
                 (short)f2bf(b.x), (short)f2bf(b.y), (short)f2bf(b.z), (short)f2bf(b.w) };
    return r;
}
__device__ inline unsigned char f2fp8(float f) {   // f32 -> e4m3 (HW RNE)
    return (unsigned char)(__builtin_amdgcn_cvt_pk_fp8_f32(f, f, 0, false) & 0xff);
}
__device__ inline f32x4 fp8x4(unsigned v) {        // 4 packed e4m3 -> f32x4
    f32x2 lo = __builtin_amdgcn_cvt_pk_f32_fp8((int)v, false);
    f32x2 hi = __builtin_amdgcn_cvt_pk_f32_fp8((int)v, true);
    f32x4 r = { lo.x, lo.y, hi.x, hi.y };
    return r;
}

// ---------------- zero (replaces pathologically slow runtime fill) ----------
__global__ void k_zero(int* __restrict__ p, int m) {
    int i = blockIdx.x * blockDim.x + threadIdx.x;
    if (i < m) p[i] = 0;
}

// ---------------- degree ----------------
__global__ void k_deg(const int* __restrict__ col, int* __restrict__ deg, int E) {
    int i = blockIdx.x * blockDim.x + threadIdx.x;
    if (i < E) atomicAdd(&deg[col[i]], 1);
}

// ---------------- hierarchical exclusive scan ----------------
__global__ __launch_bounds__(256) void k_scan1(const int* __restrict__ deg,
                                               int* __restrict__ offs,
                                               int* __restrict__ bsum, int n) {
    __shared__ int sm[256];
    int t = threadIdx.x, i = blockIdx.x * 256 + t;
    int v = (i < n) ? deg[i] : 0;
    sm[t] = v;
    __syncthreads();
    for (int off = 1; off < 256; off <<= 1) {
        int u = (t >= off) ? sm[t - off] : 0;
        __syncthreads();
        sm[t] += u;
        __syncthreads();
    }
    if (i < n) offs[i] = sm[t] - v;
    if (t == 255) bsum[blockIdx.x] = sm[255];
}

// block-sum reduce + offs final + cnt + dis + zero g pad row
__global__ __launch_bounds__(256) void k_scan3(int* __restrict__ offs,
                                               const int* __restrict__ bsum,
                                               const int* __restrict__ deg,
                                               int* __restrict__ cnt,
                                               float* __restrict__ dis,
                                               unsigned* __restrict__ g32,
                                               int n, int E) {
    __shared__ int red[256];
    int t = threadIdx.x, bid = blockIdx.x;
    red[t] = (t < 128 && t < bid) ? bsum[t] : 0;
    __syncthreads();
    for (int off = 128; off >= 1; off >>= 1) {
        if (t < off) red[t] += red[t + off];
        __syncthreads();
    }
    int base = red[0];
    int i = bid * 256 + t;
    if (i < n) {
        int o = offs[i] + base;
        offs[i] = o;
        cnt[i] = o;
        dis[i] = rsqrtf((float)(deg[i] + 1));
    }
    if (i == 0) offs[n] = E;
    if (i < 32) g32[(size_t)n * 32 + i] = 0;  // 128B pad row
}

// ---------------- MFMA GEMM core ----------------
#define GEMM_MAIN(A0, A1, A2, A3)                                               \
    f32x4 acc[8] = {};                                                          \
    _Pragma("unroll")                                                           \
    for (int nf = 0; nf < 8; ++nf) {                                            \
        const unsigned* wr = &Wl[nf * 16 + c][0];                               \
        int sx = (c & 7) << 2;                                                  \
        int b = q * 4;                                                          \
        short8 b0 = *(const short8*)(wr + ((b +  0) ^ sx));                     \
        short8 b1 = *(const short8*)(wr + ((b + 16) ^ sx));                     \
        short8 b2 = *(const short8*)(wr + ((b + 32) ^ sx));                     \
        short8 b3 = *(const short8*)(wr + ((b + 48) ^ sx));                     \
        acc[nf] = __builtin_amdgcn_mfma_f32_16x16x32_bf16(A0, b0, acc[nf], 0, 0, 0); \
        acc[nf] = __builtin_amdgcn_mfma_f32_16x16x32_bf16(A1, b1, acc[nf], 0, 0, 0); \
        acc[nf] = __builtin_amdgcn_mfma_f32_16x16x32_bf16(A2, b2, acc[nf], 0, 0, 0); \
        acc[nf] = __builtin_amdgcn_mfma_f32_16x16x32_bf16(A3, b3, acc[nf], 0, 0, 0); \
    }

#define GEMM_STORE(D0, D1, D2, D3)                                              \
    _Pragma("unroll")                                                           \
    for (int nf = 0; nf < 8; ++nf) {                                            \
        int gc = nf * 16 + c;                                                   \
        g[(size_t)(rb + q * 4 + 0) * 128 + gc] = f2fp8(acc[nf][0] * (D0));      \
        g[(size_t)(rb + q * 4 + 1) * 128 + gc] = f2fp8(acc[nf][1] * (D1));      \
        g[(size_t)(rb + q * 4 + 2) * 128 + gc] = f2fp8(acc[nf][2] * (D2));      \
        g[(size_t)(rb + q * 4 + 3) * 128 + gc] = f2fp8(acc[nf][3] * (D3));      \
    }

#define W_STAGE(TILE)                                                            \
    __shared__ unsigned Wl[128][64];                                             \
    int tid = threadIdx.x;                                                       \
    {                                                                            \
        int nn = tid & 127, hf = tid >> 7;                                       \
        for (int qq = 0; qq < 32; ++qq) {                                        \
            int k2 = hf * 32 + qq;                                               \
            float lo = W[(size_t)(2 * k2) * 128 + nn];                           \
            float hi = W[(size_t)(2 * k2 + 1) * 128 + nn];                       \
            Wl[nn][k2 ^ ((nn & 7) << 2)] = ((unsigned)f2bf(hi) << 16) | f2bf(lo);\
        }                                                                        \
    }                                                                            \
    __syncthreads();                                                             \
    int w = tid >> 6, l = tid & 63;                                              \
    int rb = (TILE) * 64 + w * 16;                                               \
    int c = l & 15, q = l >> 4;

// Layers 1..: A from bf16 hb; dis applied at epilogue (pre-scaled g rows)
__global__ __launch_bounds__(256) void k_gemm(const unsigned* __restrict__ hb,
                                              const float* __restrict__ W,
                                              const float* __restrict__ dis,
                                              unsigned char* __restrict__ g, int n) {
    W_STAGE(blockIdx.x)
    const short8* arow = (const short8*)(hb + (size_t)(rb + c) * 64);
    short8 a0 = __builtin_nontemporal_load(&arow[q]);
    short8 a1 = __builtin_nontemporal_load(&arow[4 + q]);
    short8 a2 = __builtin_nontemporal_load(&arow[8 + q]);
    short8 a3 = __builtin_nontemporal_load(&arow[12 + q]);
    GEMM_MAIN(a0, a1, a2, a3)
    float d0 = dis[rb + q * 4 + 0], d1 = dis[rb + q * 4 + 1];
    float d2 = dis[rb + q * 4 + 2], d3 = dis[rb + q * 4 + 3];
    GEMM_STORE(d0, d1, d2, d3)
}

// Fused: blocks [0, n/64) = gemm0 from f32 x with dis epilogue;
// blocks [n/64, ...) = CSR build (independent, overlapped).
__global__ __launch_bounds__(256) void k_l0b(const float* __restrict__ x,
                                             const float* __restrict__ W,
                                             const float* __restrict__ dis,
                                             unsigned char* __restrict__ g,
                                             const int* __restrict__ rowp,
                                             const int* __restrict__ colp,
                                             int* __restrict__ cnt,
                                             ushort* __restrict__ csru,
                                             int n, int E) {
    int gtiles = n >> 6;
    if ((int)blockIdx.x >= gtiles) {
        int i = ((int)blockIdx.x - gtiles) * 256 + threadIdx.x;
        if (i < E) {
            int cc = colp[i];
            int p = atomicAdd(&cnt[cc], 1);
            csru[p] = (ushort)rowp[i];
        }
        return;
    }
    W_STAGE((int)blockIdx.x)
    const f32x4* xr = (const f32x4*)(x + (size_t)(rb + c) * 128);
    short8 a0 = pack8(xr[q * 2 +  0], xr[q * 2 +  1]);
    short8 a1 = pack8(xr[q * 2 +  8], xr[q * 2 +  9]);
    short8 a2 = pack8(xr[q * 2 + 16], xr[q * 2 + 17]);
    short8 a3 = pack8(xr[q * 2 + 24], xr[q * 2 + 25]);
    GEMM_MAIN(a0, a1, a2, a3)
    float d0 = dis[rb + q * 4 + 0], d1 = dis[rb + q * 4 + 1];
    float d2 = dis[rb + q * 4 + 2], d3 = dis[rb + q * 4 + 3];
    GEMM_STORE(d0, d1, d2, d3)
}

// ---- gather: out = relu(resid + dis[c]*(g[c] + sum g[nbr]) + b), g pre-scaled --
// 2 nodes/wave (32-lane halves), 4B/lane/row. Whole <=32-row chunk issued
// before accumulation; tail rounded to 8 with zero pad row. Epilogue prefetched.
__global__ __launch_bounds__(256) void k_gather(const unsigned* __restrict__ g32,
                                                unsigned* __restrict__ hb,
                                                const float* __restrict__ dis,
                                                const float* __restrict__ bias,
                                                const int* __restrict__ offs,
                                                const ushort* __restrict__ csru,
                                                const float* __restrict__ xres,
                                                float* __restrict__ outp,
                                                int n, int use_x, int last) {
    int wid = threadIdx.x >> 6, lane = threadIdx.x & 63;
    int sel = lane >> 5, hl = lane & 31;
    int node = blockIdx.x * 8 + wid * 2 + sel;
    if (node >= n) return;

    // prefetch epilogue operands (latency hides under the neighbor loop)
    float dn = dis[node];
    f32x4 bv = ((const f32x4*)bias)[hl];
    f32x4 hv;
    if (use_x) {
        hv = __builtin_nontemporal_load(&((const f32x4*)xres)[(size_t)node * 32 + hl]);
    } else {
        u32x2 h2 = __builtin_nontemporal_load(&((const u32x2*)hb)[(size_t)node * 32 + hl]);
        hv = bf4(h2);
    }

    f32x4 acc = fp8x4(g32[(size_t)node * 32 + hl]);   // self-loop (pre-scaled)
    int s = offs[node];
    int deg = offs[node + 1] - s;
    for (int j0 = 0; j0 < deg; j0 += 32) {
        int rem = deg - j0;
        int m = rem < 32 ? rem : 32;
        int idx = (hl < m) ? (int)__builtin_nontemporal_load(&csru[s + j0 + hl]) : n;
        int mc = (m + 7) & ~7;
        unsigned v[32];
#pragma unroll
        for (int b = 0; b < 4; ++b) {
            if (b * 8 < mc) {
#pragma unroll
                for (int u = 0; u < 8; ++u) {
                    int r = __shfl(idx, b * 8 + u, 32);
                    v[b * 8 + u] = g32[(size_t)r * 32 + hl];
                }
            }
        }
#pragma unroll
        for (int b = 0; b < 4; ++b) {
            if (b * 8 < mc) {
                f32x4 s0 = (fp8x4(v[b * 8 + 0]) + fp8x4(v[b * 8 + 1])) +
                           (fp8x4(v[b * 8 + 2]) + fp8x4(v[b * 8 + 3]));
                f32x4 s1 = (fp8x4(v[b * 8 + 4]) + fp8x4(v[b * 8 + 5])) +
                           (fp8x4(v[b * 8 + 6]) + fp8x4(v[b * 8 + 7]));
                acc += s0 + s1;
            }
        }
    }

    f32x4 o = acc * dn + hv + bv;
    o.x = fmaxf(o.x, 0.f); o.y = fmaxf(o.y, 0.f);
    o.z = fmaxf(o.z, 0.f); o.w = fmaxf(o.w, 0.f);
    if (last) {
        __builtin_nontemporal_store(o, &((f32x4*)outp)[(size_t)node * 32 + hl]);
    } else {
        u32x2 pk;
        pk.x = ((unsigned)f2bf(o.y) << 16) | f2bf(o.x);
        pk.y = ((unsigned)f2bf(o.w) << 16) | f2bf(o.z);
        __builtin_nontemporal_store(pk, &((u32x2*)hb)[(size_t)node * 32 + hl]);
    }
}

static inline size_t al256(size_t x) { return (x + 255) & ~(size_t)255; }

extern "C" void kernel_launch(void* const* d_in, const int* in_sizes, int n_in,
                              void* d_out, int out_size, void* d_ws, size_t ws_size,
                              hipStream_t stream) {
    const float* x  = (const float*)d_in[0];
    const int*   ei = (const int*)d_in[1];
    const float* Ws = (const float*)d_in[2];
    const float* bs = (const float*)d_in[3];
    int n  = in_sizes[0] / 128;          // 32768 nodes
    int E  = in_sizes[1] / 2;            // 524288 edges
    int NL = in_sizes[2] / (128 * 128);  // 3 layers
    const int* rowp = ei;
    const int* colp = ei + E;

    char* ws = (char*)d_ws;
    size_t gplane  = al256((size_t)(n + 1) * 128);   // fp8 rows, 128B
    size_t hplane  = al256((size_t)(n + 1) * 256);   // bf16 rows, 256B
    unsigned char* g  = (unsigned char*)ws;
    unsigned*      hb = (unsigned*)(ws + gplane);
    char* p = ws + gplane + hplane;
    float* dis  = (float*)p;               p += al256((size_t)n * 4);
    int*   deg  = (int*)p;                 p += al256((size_t)n * 4);
    int*   offs = (int*)p;                 p += al256((size_t)(n + 1) * 4);
    int*   cnt  = (int*)p;                 p += al256((size_t)n * 4);
    int*   bsum = (int*)p;                 p += 512;
    ushort* csru = (ushort*)p;

    int nb = (n + 255) / 256;            // 128 scan blocks
    int gtiles = n / 64;                 // 512
    int eblocks = (E + 255) / 256;       // 2048

    k_zero<<<nb, 256, 0, stream>>>(deg, n);
    k_deg<<<eblocks, 256, 0, stream>>>(colp, deg, E);
    k_scan1<<<nb, 256, 0, stream>>>(deg, offs, bsum, n);
    k_scan3<<<nb, 256, 0, stream>>>(offs, bsum, deg, cnt, dis, (unsigned*)g, n, E);
    // gemm0 (with dis epilogue) overlapped with CSR build
    k_l0b<<<gtiles + eblocks, 256, 0, stream>>>(x, Ws, dis, g, rowp, colp,
                                                cnt, csru, n, E);

    for (int l = 0; l < NL; ++l) {
        int last = (l + 1 == NL);
        if (l > 0)
            k_gemm<<<gtiles, 256, 0, stream>>>(hb, Ws + (size_t)l * 128 * 128,
                                               dis, g, n);
        k_gather<<<(n + 7) / 8, 256, 0, stream>>>((const unsigned*)g, hb, dis,
                                                  bs + (size_t)l * 128,
                                                  offs, csru, x,
                                                  (float*)d_out, n,
                                                  l == 0, last);
    }
}

// Round 14
// 135.375 us; speedup vs baseline: 1.2462x; 1.0096x over previous
//
#include <hip/hip_runtime.h>

// GCN: 3 layers, h = relu(h + GCNConv(h)), fixed graph, f32 in/out.
// Fused pipeline: zero -> deg -> scan1 -> scan3 ->
//   l0b  (gemm0 || CSR build || W1,W2 transpose)      -> g_a
//   kgq  (gather l0 from g_a + gemm l1 via LDS h-tile) -> g_b
//   kgq  (gather l1 from g_b + gemm l2 via LDS h-tile) -> g_a
//   kgather (last: gather l2 from g_a -> f32 out)
// g planes fp8 e4m3 (128B rows, dis-prescaled), ping-pong to avoid races.

typedef __attribute__((ext_vector_type(8))) short short8;   // 8 bf16 = 4 VGPR
typedef __attribute__((ext_vector_type(4))) float f32x4;
typedef __attribute__((ext_vector_type(2))) float f32x2;
typedef __attribute__((ext_vector_type(2))) unsigned u32x2;

__device__ inline ushort f2bf(float f) {           // RNE f32 -> bf16
    union { float f; unsigned u; } v; v.f = f;
    unsigned u = v.u;
    return (ushort)((u + 0x7fffu + ((u >> 16) & 1u)) >> 16);
}
__device__ inline float2 bf2f(unsigned u) {
    union { unsigned i; float f; } a, b;
    a.i = u << 16;
    b.i = u & 0xffff0000u;
    return make_float2(a.f, b.f);
}
__device__ inline f32x4 bf4(u32x2 v) {
    float2 a = bf2f(v.x), b = bf2f(v.y);
    f32x4 r = { a.x, a.y, b.x, b.y };
    return r;
}
__device__ inline short8 pack8(f32x4 a, f32x4 b) {
    short8 r = { (short)f2bf(a.x), (short)f2bf(a.y), (short)f2bf(a.z), (short)f2bf(a.w),
                 (short)f2bf(b.x), (short)f2bf(b.y), (short)f2bf(b.z), (short)f2bf(b.w) };
    return r;
}
__device__ inline unsigned char f2fp8(float f) {
    return (unsigned char)(__builtin_amdgcn_cvt_pk_fp8_f32(f, f, 0, false) & 0xff);
}
__device__ inline f32x4 fp8x4(unsigned v) {
    f32x2 lo = __builtin_amdgcn_cvt_pk_f32_fp8((int)v, false);
    f32x2 hi = __builtin_amdgcn_cvt_pk_f32_fp8((int)v, true);
    f32x4 r = { lo.x, lo.y, hi.x, hi.y };
    return r;
}

// ---------------- zero ----------------
__global__ void k_zero(int* __restrict__ p, int m) {
    int i = blockIdx.x * blockDim.x + threadIdx.x;
    if (i < m) p[i] = 0;
}

// ---------------- degree ----------------
__global__ void k_deg(const int* __restrict__ col, int* __restrict__ deg, int E) {
    int i = blockIdx.x * blockDim.x + threadIdx.x;
    if (i < E) atomicAdd(&deg[col[i]], 1);
}

// ---------------- scan ----------------
__global__ __launch_bounds__(256) void k_scan1(const int* __restrict__ deg,
                                               int* __restrict__ offs,
                                               int* __restrict__ bsum, int n) {
    __shared__ int sm[256];
    int t = threadIdx.x, i = blockIdx.x * 256 + t;
    int v = (i < n) ? deg[i] : 0;
    sm[t] = v;
    __syncthreads();
    for (int off = 1; off < 256; off <<= 1) {
        int u = (t >= off) ? sm[t - off] : 0;
        __syncthreads();
        sm[t] += u;
        __syncthreads();
    }
    if (i < n) offs[i] = sm[t] - v;
    if (t == 255) bsum[blockIdx.x] = sm[255];
}

__global__ __launch_bounds__(256) void k_scan3(int* __restrict__ offs,
                                               const int* __restrict__ bsum,
                                               const int* __restrict__ deg,
                                               int* __restrict__ cnt,
                                               float* __restrict__ dis,
                                               unsigned* __restrict__ ga32,
                                               unsigned* __restrict__ gb32,
                                               int n, int E) {
    __shared__ int red[256];
    int t = threadIdx.x, bid = blockIdx.x;
    red[t] = (t < 128 && t < bid) ? bsum[t] : 0;
    __syncthreads();
    for (int off = 128; off >= 1; off >>= 1) {
        if (t < off) red[t] += red[t + off];
        __syncthreads();
    }
    int base = red[0];
    int i = bid * 256 + t;
    if (i < n) {
        int o = offs[i] + base;
        offs[i] = o;
        cnt[i] = o;
        dis[i] = rsqrtf((float)(deg[i] + 1));
    }
    if (i == 0) offs[n] = E;
    if (i < 32) {                       // zero 128B pad rows of both planes
        ga32[(size_t)n * 32 + i] = 0;
        gb32[(size_t)n * 32 + i] = 0;
    }
}

// ---------------- MFMA gemm0 core (f32 x input, LDS W transpose) ------------
#define W_STAGE(TILE)                                                            \
    __shared__ unsigned Wl[128][64];                                             \
    int tid = threadIdx.x;                                                       \
    {                                                                            \
        int nn = tid & 127, hf = tid >> 7;                                       \
        for (int qq = 0; qq < 32; ++qq) {                                        \
            int k2 = hf * 32 + qq;                                               \
            float lo = W[(size_t)(2 * k2) * 128 + nn];                           \
            float hi = W[(size_t)(2 * k2 + 1) * 128 + nn];                       \
            Wl[nn][k2 ^ ((nn & 7) << 2)] = ((unsigned)f2bf(hi) << 16) | f2bf(lo);\
        }                                                                        \
    }                                                                            \
    __syncthreads();                                                             \
    int w = tid >> 6, l = tid & 63;                                              \
    int rb = (TILE) * 64 + w * 16;                                               \
    int c = l & 15, q = l >> 4;

// Fused: blocks [0,gtiles) gemm0; [gtiles, gtiles+eblocks) CSR build;
// last NL-1 blocks transpose W^(l) -> Wt_l (packed bf16 [n][k2]).
__global__ __launch_bounds__(256) void k_l0b(const float* __restrict__ x,
                                             const float* __restrict__ W,
                                             const float* __restrict__ dis,
                                             unsigned char* __restrict__ g,
                                             const int* __restrict__ rowp,
                                             const int* __restrict__ colp,
                                             int* __restrict__ cnt,
                                             ushort* __restrict__ csru,
                                             unsigned* __restrict__ Wt,
                                             int n, int E, int nwt) {
    int gtiles = n >> 6;
    if ((int)blockIdx.x >= gtiles + ((E + 255) >> 8)) {      // W transpose
        int wl = (int)blockIdx.x - gtiles - ((E + 255) >> 8);
        if (wl < nwt) {
            const float* Wsrc = W + (size_t)(wl + 1) * 128 * 128;
            unsigned* Wd = Wt + (size_t)wl * 128 * 64;
            int nn = threadIdx.x & 127, hf = threadIdx.x >> 7;
            for (int qq = 0; qq < 32; ++qq) {
                int k2 = hf * 32 + qq;
                float lo = Wsrc[(size_t)(2 * k2) * 128 + nn];
                float hi = Wsrc[(size_t)(2 * k2 + 1) * 128 + nn];
                Wd[nn * 64 + k2] = ((unsigned)f2bf(hi) << 16) | f2bf(lo);
            }
        }
        return;
    }
    if ((int)blockIdx.x >= gtiles) {                         // CSR build
        int i = ((int)blockIdx.x - gtiles) * 256 + threadIdx.x;
        if (i < E) {
            int cc = colp[i];
            int p = atomicAdd(&cnt[cc], 1);
            csru[p] = (ushort)rowp[i];
        }
        return;
    }
    W_STAGE((int)blockIdx.x)
    const f32x4* xr = (const f32x4*)(x + (size_t)(rb + c) * 128);
    short8 a0 = pack8(xr[q * 2 +  0], xr[q * 2 +  1]);
    short8 a1 = pack8(xr[q * 2 +  8], xr[q * 2 +  9]);
    short8 a2 = pack8(xr[q * 2 + 16], xr[q * 2 + 17]);
    short8 a3 = pack8(xr[q * 2 + 24], xr[q * 2 + 25]);
    f32x4 acc[8] = {};
#pragma unroll
    for (int nf = 0; nf < 8; ++nf) {
        const unsigned* wr = &Wl[nf * 16 + c][0];
        int sx = (c & 7) << 2;
        int b = q * 4;
        short8 b0 = *(const short8*)(wr + ((b +  0) ^ sx));
        short8 b1 = *(const short8*)(wr + ((b + 16) ^ sx));
        short8 b2 = *(const short8*)(wr + ((b + 32) ^ sx));
        short8 b3 = *(const short8*)(wr + ((b + 48) ^ sx));
        acc[nf] = __builtin_amdgcn_mfma_f32_16x16x32_bf16(a0, b0, acc[nf], 0, 0, 0);
        acc[nf] = __builtin_amdgcn_mfma_f32_16x16x32_bf16(a1, b1, acc[nf], 0, 0, 0);
        acc[nf] = __builtin_amdgcn_mfma_f32_16x16x32_bf16(a2, b2, acc[nf], 0, 0, 0);
        acc[nf] = __builtin_amdgcn_mfma_f32_16x16x32_bf16(a3, b3, acc[nf], 0, 0, 0);
    }
    float d0 = dis[rb + q * 4 + 0], d1 = dis[rb + q * 4 + 1];
    float d2 = dis[rb + q * 4 + 2], d3 = dis[rb + q * 4 + 3];
#pragma unroll
    for (int nf = 0; nf < 8; ++nf) {
        int gc = nf * 16 + c;
        g[(size_t)(rb + q * 4 + 0) * 128 + gc] = f2fp8(acc[nf][0] * d0);
        g[(size_t)(rb + q * 4 + 1) * 128 + gc] = f2fp8(acc[nf][1] * d1);
        g[(size_t)(rb + q * 4 + 2) * 128 + gc] = f2fp8(acc[nf][2] * d2);
        g[(size_t)(rb + q * 4 + 3) * 128 + gc] = f2fp8(acc[nf][3] * d3);
    }
}

// ---------------- gather inner (shared by kgq / kgather) ----------------
// 2 nodes per wave (32-lane halves); returns relu'd h row slice (4 feats/lane).
__device__ inline f32x4 gather_node(const unsigned* __restrict__ g32,
                                    const float* __restrict__ dis,
                                    const f32x4 bv, const f32x4 hv,
                                    const int* __restrict__ offs,
                                    const ushort* __restrict__ csru,
                                    int node, int hl, int n) {
    float dn = dis[node];
    f32x4 acc = fp8x4(g32[(size_t)node * 32 + hl]);   // self-loop (pre-scaled)
    int s = offs[node];
    int deg = offs[node + 1] - s;
    for (int j0 = 0; j0 < deg; j0 += 32) {
        int rem = deg - j0;
        int m = rem < 32 ? rem : 32;
        int idx = (hl < m) ? (int)__builtin_nontemporal_load(&csru[s + j0 + hl]) : n;
        int mc = (m + 7) & ~7;
        unsigned v[32];
#pragma unroll
        for (int b = 0; b < 4; ++b) {
            if (b * 8 < mc) {
#pragma unroll
                for (int u = 0; u < 8; ++u) {
                    int r = __shfl(idx, b * 8 + u, 32);
                    v[b * 8 + u] = g32[(size_t)r * 32 + hl];
                }
            }
        }
#pragma unroll
        for (int b = 0; b < 4; ++b) {
            if (b * 8 < mc) {
                f32x4 s0 = (fp8x4(v[b * 8 + 0]) + fp8x4(v[b * 8 + 1])) +
                           (fp8x4(v[b * 8 + 2]) + fp8x4(v[b * 8 + 3]));
                f32x4 s1 = (fp8x4(v[b * 8 + 4]) + fp8x4(v[b * 8 + 5])) +
                           (fp8x4(v[b * 8 + 6]) + fp8x4(v[b * 8 + 7]));
                acc += s0 + s1;
            }
        }
    }
    f32x4 o = acc * dn + hv + bv;
    o.x = fmaxf(o.x, 0.f); o.y = fmaxf(o.y, 0.f);
    o.z = fmaxf(o.z, 0.f); o.w = fmaxf(o.w, 0.f);
    return o;
}

// ---------------- fused gather(l) + gemm(l+1) ----------------
// Block = 32 nodes. Phase 1: gather -> LDS bf16 tile [32][68] (+hb for next
// residual). Phase 2: MFMA from LDS A + global Wt B -> gout (fp8, dis-scaled).
__global__ __launch_bounds__(256) void k_gq(const unsigned* __restrict__ gin,
                                            unsigned char* __restrict__ gout,
                                            unsigned* __restrict__ hb,
                                            const float* __restrict__ dis,
                                            const float* __restrict__ bias,
                                            const int* __restrict__ offs,
                                            const ushort* __restrict__ csru,
                                            const float* __restrict__ xres,
                                            const unsigned* __restrict__ Wt,
                                            int n, int use_x) {
    __shared__ unsigned Hs[32][68];     // packed bf16 pairs, padded rows
    int tid = threadIdx.x;
    int w = tid >> 6, lane = tid & 63;
    int sel = lane >> 5, hl = lane & 31;

    // ---- phase 1: gather 32 nodes (4 waves x 4 iters x 2 nodes) ----
    for (int it = 0; it < 4; ++it) {
        int nl = w * 8 + it * 2 + sel;
        int node = blockIdx.x * 32 + nl;
        f32x4 bv = ((const f32x4*)bias)[hl];
        f32x4 hv;
        if (use_x) {
            hv = __builtin_nontemporal_load(&((const f32x4*)xres)[(size_t)node * 32 + hl]);
        } else {
            u32x2 h2 = __builtin_nontemporal_load(&((const u32x2*)hb)[(size_t)node * 32 + hl]);
            hv = bf4(h2);
        }
        f32x4 o = gather_node(gin, dis, bv, hv, offs, csru, node, hl, n);
        u32x2 pk;
        pk.x = ((unsigned)f2bf(o.y) << 16) | f2bf(o.x);
        pk.y = ((unsigned)f2bf(o.w) << 16) | f2bf(o.z);
        __builtin_nontemporal_store(pk, &((u32x2*)hb)[(size_t)node * 32 + hl]);
        *(u32x2*)&Hs[nl][2 * hl] = pk;
    }
    __syncthreads();

    // ---- phase 2: gemm for next layer, 16 rows x 64 cols per wave ----
    int c = lane & 15, q = lane >> 4;
    int r16 = (w & 1) * 16, ch2 = w >> 1;
    const short8* ar = (const short8*)&Hs[r16 + c][0];  // row stride 68 dwords
    short8 a0 = *(const short8*)&Hs[r16 + c][q * 4 +  0];
    short8 a1 = *(const short8*)&Hs[r16 + c][q * 4 + 16];
    short8 a2 = *(const short8*)&Hs[r16 + c][q * 4 + 32];
    short8 a3 = *(const short8*)&Hs[r16 + c][q * 4 + 48];
    (void)ar;
    f32x4 acc[4] = {};
#pragma unroll
    for (int nf = 0; nf < 4; ++nf) {
        const short8* brow = (const short8*)(Wt + (size_t)(ch2 * 64 + nf * 16 + c) * 64);
        short8 b0 = brow[q], b1 = brow[4 + q], b2 = brow[8 + q], b3 = brow[12 + q];
        acc[nf] = __builtin_amdgcn_mfma_f32_16x16x32_bf16(a0, b0, acc[nf], 0, 0, 0);
        acc[nf] = __builtin_amdgcn_mfma_f32_16x16x32_bf16(a1, b1, acc[nf], 0, 0, 0);
        acc[nf] = __builtin_amdgcn_mfma_f32_16x16x32_bf16(a2, b2, acc[nf], 0, 0, 0);
        acc[nf] = __builtin_amdgcn_mfma_f32_16x16x32_bf16(a3, b3, acc[nf], 0, 0, 0);
    }
    int grow = blockIdx.x * 32 + r16 + q * 4;
    float d0 = dis[grow + 0], d1 = dis[grow + 1];
    float d2 = dis[grow + 2], d3 = dis[grow + 3];
#pragma unroll
    for (int nf = 0; nf < 4; ++nf) {
        int gc = ch2 * 64 + nf * 16 + c;
        gout[(size_t)(grow + 0) * 128 + gc] = f2fp8(acc[nf][0] * d0);
        gout[(size_t)(grow + 1) * 128 + gc] = f2fp8(acc[nf][1] * d1);
        gout[(size_t)(grow + 2) * 128 + gc] = f2fp8(acc[nf][2] * d2);
        gout[(size_t)(grow + 3) * 128 + gc] = f2fp8(acc[nf][3] * d3);
    }
}

// ---------------- last-layer gather (f32 out) ----------------
__global__ __launch_bounds__(256) void k_gather(const unsigned* __restrict__ g32,
                                                const unsigned* __restrict__ hb,
                                                const float* __restrict__ dis,
                                                const float* __restrict__ bias,
                                                const int* __restrict__ offs,
                                                const ushort* __restrict__ csru,
                                                float* __restrict__ outp, int n) {
    int wid = threadIdx.x >> 6, lane = threadIdx.x & 63;
    int sel = lane >> 5, hl = lane & 31;
    int node = blockIdx.x * 8 + wid * 2 + sel;
    if (node >= n) return;
    f32x4 bv = ((const f32x4*)bias)[hl];
    u32x2 h2 = __builtin_nontemporal_load(&((const u32x2*)hb)[(size_t)node * 32 + hl]);
    f32x4 hv = bf4(h2);
    f32x4 o = gather_node(g32, dis, bv, hv, offs, csru, node, hl, n);
    __builtin_nontemporal_store(o, &((f32x4*)outp)[(size_t)node * 32 + hl]);
}

static inline size_t al256(size_t x) { return (x + 255) & ~(size_t)255; }

extern "C" void kernel_launch(void* const* d_in, const int* in_sizes, int n_in,
                              void* d_out, int out_size, void* d_ws, size_t ws_size,
                              hipStream_t stream) {
    const float* x  = (const float*)d_in[0];
    const int*   ei = (const int*)d_in[1];
    const float* Ws = (const float*)d_in[2];
    const float* bs = (const float*)d_in[3];
    int n  = in_sizes[0] / 128;          // 32768 nodes
    int E  = in_sizes[1] / 2;            // 524288 edges
    int NL = in_sizes[2] / (128 * 128);  // 3 layers
    const int* rowp = ei;
    const int* colp = ei + E;

    char* ws = (char*)d_ws;
    size_t gplane  = al256((size_t)(n + 1) * 128);   // fp8 rows, 128B
    size_t hplane  = al256((size_t)(n + 1) * 256);   // bf16 rows, 256B
    unsigned char* ga = (unsigned char*)ws;
    unsigned char* gb = (unsigned char*)(ws + gplane);
    unsigned*      hb = (unsigned*)(ws + 2 * gplane);
    char* p = ws + 2 * gplane + hplane;
    float* dis  = (float*)p;               p += al256((size_t)n * 4);
    int*   deg  = (int*)p;                 p += al256((size_t)n * 4);
    int*   offs = (int*)p;                 p += al256((size_t)(n + 1) * 4);
    int*   cnt  = (int*)p;                 p += al256((size_t)n * 4);
    int*   bsum = (int*)p;                 p += 512;
    unsigned* Wt = (unsigned*)p;           p += al256((size_t)(NL - 1) * 128 * 64 * 4);
    ushort* csru = (ushort*)p;

    int nb = (n + 255) / 256;            // 128 scan blocks
    int gtiles = n / 64;                 // 512
    int eblocks = (E + 255) / 256;       // 2048

    k_zero<<<nb, 256, 0, stream>>>(deg, n);
    k_deg<<<eblocks, 256, 0, stream>>>(colp, deg, E);
    k_scan1<<<nb, 256, 0, stream>>>(deg, offs, bsum, n);
    k_scan3<<<nb, 256, 0, stream>>>(offs, bsum, deg, cnt, dis,
                                    (unsigned*)ga, (unsigned*)gb, n, E);
    // gemm0 || CSR build || W1,W2 transpose
    k_l0b<<<gtiles + eblocks + (NL - 1), 256, 0, stream>>>(
        x, Ws, dis, ga, rowp, colp, cnt, csru, Wt, n, E, NL - 1);

    unsigned char* gcur = ga;
    unsigned char* gnxt = gb;
    for (int l = 0; l < NL - 1; ++l) {
        k_gq<<<n / 32, 256, 0, stream>>>((const unsigned*)gcur, gnxt, hb, dis,
                                         bs + (size_t)l * 128, offs, csru, x,
                                         Wt + (size_t)l * 128 * 64, n, l == 0);
        unsigned char* t = gcur; gcur = gnxt; gnxt = t;
    }
    k_gather<<<(n + 7) / 8, 256, 0, stream>>>((const unsigned*)gcur, hb, dis,
                                              bs + (size_t)(NL - 1) * 128,
                                              offs, csru, (float*)d_out, n);
}